// Round 1
// baseline (683.198 us; speedup 1.0000x reference)
//
#include <hip/hip_runtime.h>

#define N_NODES 100000
#define N_EDGES 1600000

// ---------------- CSR build ----------------

__global__ void hist_k(const int* __restrict__ dst, int* __restrict__ count, int E) {
    int e = blockIdx.x * 256 + threadIdx.x;
    if (e < E) atomicAdd(&count[dst[e]], 1);
}

__global__ void dis_k(const int* __restrict__ count, float* __restrict__ dis, int n) {
    int i = blockIdx.x * 256 + threadIdx.x;
    if (i < n) dis[i] = rsqrtf((float)(count[i] + 1));  // +1 self-loop
}

__global__ void scan_blocks_k(const int* __restrict__ count, int* __restrict__ row_start,
                              int* __restrict__ bsum, int n) {
    __shared__ int s[256];
    int tid = threadIdx.x;
    int i = blockIdx.x * 256 + tid;
    int v = (i < n) ? count[i] : 0;
    s[tid] = v; __syncthreads();
    for (int off = 1; off < 256; off <<= 1) {
        int t = 0;
        if (tid >= off) t = s[tid - off];
        __syncthreads();
        s[tid] += t;
        __syncthreads();
    }
    if (i < n) row_start[i] = s[tid] - v;        // exclusive within block
    if (tid == 255) bsum[blockIdx.x] = s[255];   // block total
}

__global__ void scan_sums_k(int* __restrict__ bsum, int nb) {
    __shared__ int s[512];
    int tid = threadIdx.x;
    int v = (tid < nb) ? bsum[tid] : 0;
    s[tid] = v; __syncthreads();
    for (int off = 1; off < 512; off <<= 1) {
        int t = 0;
        if (tid >= off) t = s[tid - off];
        __syncthreads();
        s[tid] += t;
        __syncthreads();
    }
    if (tid < nb) bsum[tid] = s[tid] - v;        // exclusive
}

__global__ void add_off_k(int* __restrict__ row_start, int* __restrict__ fill,
                          const int* __restrict__ bsum, int n, int E) {
    int i = blockIdx.x * 256 + threadIdx.x;
    if (i < n) {
        int r = row_start[i] + bsum[blockIdx.x];
        row_start[i] = r;
        fill[i] = r;
    }
    if (i == 0) row_start[n] = E;
}

__global__ void scatter_k(const int* __restrict__ src, const int* __restrict__ dst,
                          const float* __restrict__ dis, int* __restrict__ fill,
                          int* __restrict__ esrc, float* __restrict__ enorm, int E) {
    int e = blockIdx.x * 256 + threadIdx.x;
    if (e < E) {
        int s = src[e], d = dst[e];
        int pos = atomicAdd(&fill[d], 1);
        esrc[pos] = s;
        enorm[pos] = dis[s] * dis[d];
    }
}

// ---------------- Dense transform: Y[nrows x OUTF] = X[nrows x 128] @ W[128 x OUTF] ----------------

template <int OUTF>
__global__ void gemm_k(const float* __restrict__ X, const float* __restrict__ W,
                       float* __restrict__ Y, int nrows) {
    constexpr int C4 = OUTF / 4;      // float4 column groups
    constexpr int RC = 256 / C4;      // rows concurrent per iteration
    constexpr int TR = 128;           // tile rows per block
    __shared__ float4 ws4[128 * C4];  // OUTF=128: 64 KB, OUTF=64: 32 KB
    int tid = threadIdx.x;
    for (int j = tid; j < 128 * C4; j += 256) ws4[j] = ((const float4*)W)[j];
    __syncthreads();
    int c4 = tid % C4, rl = tid / C4;
    int rbase = blockIdx.x * TR;
    for (int r0 = 0; r0 < TR; r0 += RC) {
        int row = rbase + r0 + rl;
        if (row < nrows) {
            const float4* xr = (const float4*)(X + (size_t)row * 128);
            float4 acc = make_float4(0.f, 0.f, 0.f, 0.f);
#pragma unroll
            for (int k4 = 0; k4 < 32; ++k4) {
                float4 xv = xr[k4];
                float4 w0 = ws4[(k4 * 4 + 0) * C4 + c4];
                float4 w1 = ws4[(k4 * 4 + 1) * C4 + c4];
                float4 w2 = ws4[(k4 * 4 + 2) * C4 + c4];
                float4 w3 = ws4[(k4 * 4 + 3) * C4 + c4];
                acc.x += xv.x * w0.x + xv.y * w1.x + xv.z * w2.x + xv.w * w3.x;
                acc.y += xv.x * w0.y + xv.y * w1.y + xv.z * w2.y + xv.w * w3.y;
                acc.z += xv.x * w0.z + xv.y * w1.z + xv.z * w2.z + xv.w * w3.z;
                acc.w += xv.x * w0.w + xv.y * w1.w + xv.z * w2.w + xv.w * w3.w;
            }
            ((float4*)(Y + (size_t)row * OUTF))[c4] = acc;
        }
    }
}

// ---------------- Aggregation (1 wave per node), fused bias + PReLU ----------------

// HID=128: each lane owns a float2 (cols 2*lane, 2*lane+1)
__global__ void agg1_k(const float* __restrict__ hw, const int* __restrict__ row_start,
                       const int* __restrict__ esrc, const float* __restrict__ enorm,
                       const float* __restrict__ dis, const float* __restrict__ bias,
                       const float* __restrict__ aslope, float* __restrict__ out, int n) {
    int wid = (blockIdx.x * 256 + threadIdx.x) >> 6;
    int lane = threadIdx.x & 63;
    if (wid >= n) return;
    const float2* base = (const float2*)hw;
    float ax = 0.f, ay = 0.f;
    int e0 = row_start[wid], e1 = row_start[wid + 1];
    for (int e = e0; e < e1; ++e) {
        int s = esrc[e];
        float nr = enorm[e];
        float2 v = base[(size_t)s * 64 + lane];
        ax += nr * v.x;
        ay += nr * v.y;
    }
    float dn = dis[wid];
    float sw = dn * dn;
    float2 v = base[(size_t)wid * 64 + lane];
    ax += sw * v.x;
    ay += sw * v.y;
    float2 b = ((const float2*)bias)[lane];
    float al = aslope[0];
    ax += b.x; ay += b.y;
    ax = (ax >= 0.f) ? ax : al * ax;
    ay = (ay >= 0.f) ? ay : al * ay;
    ((float2*)out)[(size_t)wid * 64 + lane] = make_float2(ax, ay);
}

// OUT=64: each lane owns 1 column
__global__ void agg2_k(const float* __restrict__ hw, const int* __restrict__ row_start,
                       const int* __restrict__ esrc, const float* __restrict__ enorm,
                       const float* __restrict__ dis, const float* __restrict__ bias,
                       const float* __restrict__ aslope, float* __restrict__ out, int n) {
    int wid = (blockIdx.x * 256 + threadIdx.x) >> 6;
    int lane = threadIdx.x & 63;
    if (wid >= n) return;
    float acc = 0.f;
    int e0 = row_start[wid], e1 = row_start[wid + 1];
    for (int e = e0; e < e1; ++e) {
        int s = esrc[e];
        acc += enorm[e] * hw[(size_t)s * 64 + lane];
    }
    float dn = dis[wid];
    acc += dn * dn * hw[(size_t)wid * 64 + lane];
    acc += bias[lane];
    float al = aslope[0];
    acc = (acc >= 0.f) ? acc : al * acc;
    out[(size_t)wid * 64 + lane] = acc;
}

// ---------------- launch ----------------

extern "C" void kernel_launch(void* const* d_in, const int* in_sizes, int n_in,
                              void* d_out, int out_size, void* d_ws, size_t ws_size,
                              hipStream_t stream) {
    const float* x  = (const float*)d_in[0];
    const int*   ei = (const int*)d_in[1];
    const int*   src = ei;
    const int*   dst = ei + N_EDGES;
    const float* W1 = (const float*)d_in[2];
    const float* b1 = (const float*)d_in[3];
    const float* W2 = (const float*)d_in[4];
    const float* b2 = (const float*)d_in[5];
    const float* a  = (const float*)d_in[6];
    float* out = (float*)d_out;

    char* ws = (char*)d_ws;
    size_t off = 0;
    auto alloc = [&](size_t bytes) -> void* {
        void* p = ws + off;
        off += (bytes + 255) & ~(size_t)255;
        return p;
    };
    int*   count     = (int*)alloc((size_t)N_NODES * 4);
    int*   row_start = (int*)alloc((size_t)(N_NODES + 1) * 4);
    int*   fill      = (int*)alloc((size_t)N_NODES * 4);
    float* dis       = (float*)alloc((size_t)N_NODES * 4);
    int*   bsum      = (int*)alloc(512 * 4);
    int*   esrc      = (int*)alloc((size_t)N_EDGES * 4);
    float* enorm     = (float*)alloc((size_t)N_EDGES * 4);
    float* bufA      = (float*)alloc((size_t)N_NODES * 128 * 4);  // hw1, then hw2
    float* bufB      = (float*)alloc((size_t)N_NODES * 128 * 4);  // h

    hipMemsetAsync(count, 0, (size_t)N_NODES * 4, stream);

    int gE = (N_EDGES + 255) / 256;   // 6250
    int gN = (N_NODES + 255) / 256;   // 391

    hist_k<<<gE, 256, 0, stream>>>(dst, count, N_EDGES);
    dis_k<<<gN, 256, 0, stream>>>(count, dis, N_NODES);
    scan_blocks_k<<<gN, 256, 0, stream>>>(count, row_start, bsum, N_NODES);
    scan_sums_k<<<1, 512, 0, stream>>>(bsum, gN);
    add_off_k<<<gN, 256, 0, stream>>>(row_start, fill, bsum, N_NODES, N_EDGES);
    scatter_k<<<gE, 256, 0, stream>>>(src, dst, dis, fill, esrc, enorm, N_EDGES);

    int gG = (N_NODES + 127) / 128;   // 782
    int gA = (N_NODES + 3) / 4;       // 25000 (4 waves/block, 1 wave/node)

    gemm_k<128><<<gG, 256, 0, stream>>>(x, W1, bufA, N_NODES);
    agg1_k<<<gA, 256, 0, stream>>>(bufA, row_start, esrc, enorm, dis, b1, a, bufB, N_NODES);
    gemm_k<64><<<gG, 256, 0, stream>>>(bufB, W2, bufA, N_NODES);
    agg2_k<<<gA, 256, 0, stream>>>(bufA, row_start, esrc, enorm, dis, b2, a, out, N_NODES);
}

// Round 2
// 587.287 us; speedup vs baseline: 1.1633x; 1.1633x over previous
//
#include <hip/hip_runtime.h>

#define N_NODES 100000
#define N_EDGES 1600000

// ---------------- bf16 helpers (storage only; math in f32) ----------------

__device__ __forceinline__ unsigned pack_bf16x2(float a, float b) {
    unsigned ua = __float_as_uint(a), ub = __float_as_uint(b);
    unsigned ra = (ua + 0x7fffu + ((ua >> 16) & 1u)) >> 16;   // RNE
    unsigned rb = (ub + 0x7fffu + ((ub >> 16) & 1u)) >> 16;
    return ra | (rb << 16);
}
__device__ __forceinline__ float bf_lo(unsigned v) { return __uint_as_float(v << 16); }
__device__ __forceinline__ float bf_hi(unsigned v) { return __uint_as_float(v & 0xffff0000u); }

// ---------------- CSR build ----------------

__global__ void hist_k(const int* __restrict__ dst, int* __restrict__ count, int E) {
    int e = blockIdx.x * 256 + threadIdx.x;
    if (e < E) atomicAdd(&count[dst[e]], 1);
}

__global__ void dis_k(const int* __restrict__ count, float* __restrict__ dis, int n) {
    int i = blockIdx.x * 256 + threadIdx.x;
    if (i < n) dis[i] = rsqrtf((float)(count[i] + 1));  // +1 self-loop
}

__global__ void scan_blocks_k(const int* __restrict__ count, int* __restrict__ row_start,
                              int* __restrict__ bsum, int n) {
    __shared__ int s[256];
    int tid = threadIdx.x;
    int i = blockIdx.x * 256 + tid;
    int v = (i < n) ? count[i] : 0;
    s[tid] = v; __syncthreads();
    for (int off = 1; off < 256; off <<= 1) {
        int t = 0;
        if (tid >= off) t = s[tid - off];
        __syncthreads();
        s[tid] += t;
        __syncthreads();
    }
    if (i < n) row_start[i] = s[tid] - v;
    if (tid == 255) bsum[blockIdx.x] = s[255];
}

__global__ void scan_sums_k(int* __restrict__ bsum, int nb) {
    __shared__ int s[512];
    int tid = threadIdx.x;
    int v = (tid < nb) ? bsum[tid] : 0;
    s[tid] = v; __syncthreads();
    for (int off = 1; off < 512; off <<= 1) {
        int t = 0;
        if (tid >= off) t = s[tid - off];
        __syncthreads();
        s[tid] += t;
        __syncthreads();
    }
    if (tid < nb) bsum[tid] = s[tid] - v;
}

__global__ void add_off_k(int* __restrict__ row_start, int* __restrict__ fill,
                          const int* __restrict__ bsum, int n, int E) {
    int i = blockIdx.x * 256 + threadIdx.x;
    if (i < n) {
        int r = row_start[i] + bsum[blockIdx.x];
        row_start[i] = r;
        fill[i] = r;
    }
    if (i == 0) row_start[n] = E;
}

__global__ void scatter_k(const int* __restrict__ src, const int* __restrict__ dst,
                          const float* __restrict__ dis, int* __restrict__ fill,
                          uint2* __restrict__ edge, int E) {
    int e = blockIdx.x * 256 + threadIdx.x;
    if (e < E) {
        int s = src[e], d = dst[e];
        int pos = atomicAdd(&fill[d], 1);
        edge[pos] = make_uint2((unsigned)s, __float_as_uint(dis[s] * dis[d]));
    }
}

// ---- GEMM: Y[nrows x OUTF](bf16) = X[nrows x 128](f32 or bf16) @ W[128 x OUTF](f32) ----

template <int OUTF, bool INBF>
__global__ void gemm_k(const void* __restrict__ Xv, const float* __restrict__ W,
                       unsigned* __restrict__ Y, int nrows) {
    constexpr int C4 = OUTF / 4;      // float4 column groups
    constexpr int RC = 256 / C4;      // rows concurrent per iteration
    constexpr int TR = 128;           // tile rows per block
    __shared__ float4 ws4[128 * C4];
    int tid = threadIdx.x;
    for (int j = tid; j < 128 * C4; j += 256) ws4[j] = ((const float4*)W)[j];
    __syncthreads();
    int c4 = tid % C4, rl = tid / C4;
    int rbase = blockIdx.x * TR;
    for (int r0 = 0; r0 < TR; r0 += RC) {
        int row = rbase + r0 + rl;
        if (row >= nrows) continue;
        float4 acc = make_float4(0.f, 0.f, 0.f, 0.f);
#pragma unroll
        for (int k8 = 0; k8 < 16; ++k8) {
            float xv[8];
            if constexpr (INBF) {
                uint4 u = ((const uint4*)((const unsigned*)Xv + (size_t)row * 64))[k8];
                xv[0] = bf_lo(u.x); xv[1] = bf_hi(u.x);
                xv[2] = bf_lo(u.y); xv[3] = bf_hi(u.y);
                xv[4] = bf_lo(u.z); xv[5] = bf_hi(u.z);
                xv[6] = bf_lo(u.w); xv[7] = bf_hi(u.w);
            } else {
                const float4* xr = (const float4*)((const float*)Xv + (size_t)row * 128);
                float4 a = xr[2 * k8], b = xr[2 * k8 + 1];
                xv[0] = a.x; xv[1] = a.y; xv[2] = a.z; xv[3] = a.w;
                xv[4] = b.x; xv[5] = b.y; xv[6] = b.z; xv[7] = b.w;
            }
#pragma unroll
            for (int j = 0; j < 8; ++j) {
                float4 w = ws4[(k8 * 8 + j) * C4 + c4];
                acc.x += xv[j] * w.x;
                acc.y += xv[j] * w.y;
                acc.z += xv[j] * w.z;
                acc.w += xv[j] * w.w;
            }
        }
        uint2 o = make_uint2(pack_bf16x2(acc.x, acc.y), pack_bf16x2(acc.z, acc.w));
        ((uint2*)(Y + (size_t)row * (OUTF / 2)))[c4] = o;
    }
}

// ---------------- Aggregation (fused bias + PReLU) ----------------

// Layer 1: 128 bf16 cols/row = 64 uints; 1 wave/node, 1 uint/lane. Output h in bf16.
__global__ void agg1_k(const unsigned* __restrict__ hw, const int* __restrict__ row_start,
                       const uint2* __restrict__ edge, const float* __restrict__ dis,
                       const float* __restrict__ bias, const float* __restrict__ aslope,
                       unsigned* __restrict__ out, int n) {
    int wid = (blockIdx.x * 256 + threadIdx.x) >> 6;
    int lane = threadIdx.x & 63;
    if (wid >= n) return;
    float ax = 0.f, ay = 0.f;
    int e0 = row_start[wid], e1 = row_start[wid + 1];
    for (int e = e0; e < e1; ++e) {
        uint2 ed = edge[e];
        float nr = __uint_as_float(ed.y);
        unsigned v = hw[(size_t)ed.x * 64 + lane];
        ax += nr * bf_lo(v);
        ay += nr * bf_hi(v);
    }
    float dn = dis[wid];
    float sw = dn * dn;
    unsigned v = hw[(size_t)wid * 64 + lane];
    ax += sw * bf_lo(v);
    ay += sw * bf_hi(v);
    float2 b = ((const float2*)bias)[lane];
    float al = aslope[0];
    ax += b.x; ay += b.y;
    ax = (ax >= 0.f) ? ax : al * ax;
    ay = (ay >= 0.f) ? ay : al * ay;
    out[(size_t)wid * 64 + lane] = pack_bf16x2(ax, ay);
}

// Layer 2: 64 bf16 cols/row = 32 uints; half-wave per edge (2 edges/iter), f32 output.
__global__ void agg2_k(const unsigned* __restrict__ hw, const int* __restrict__ row_start,
                       const uint2* __restrict__ edge, const float* __restrict__ dis,
                       const float* __restrict__ bias, const float* __restrict__ aslope,
                       float* __restrict__ out, int n) {
    int wid = (blockIdx.x * 256 + threadIdx.x) >> 6;
    int lane = threadIdx.x & 63;
    if (wid >= n) return;
    int slot = lane >> 5;   // which edge of the pair
    int c = lane & 31;      // uint column (cols 2c, 2c+1)
    float ax = 0.f, ay = 0.f;
    int e0 = row_start[wid], e1 = row_start[wid + 1];
    for (int e = e0; e < e1; e += 2) {
        int ee = e + slot;
        if (ee < e1) {
            uint2 ed = edge[ee];
            float nr = __uint_as_float(ed.y);
            unsigned v = hw[(size_t)ed.x * 32 + c];
            ax += nr * bf_lo(v);
            ay += nr * bf_hi(v);
        }
    }
    ax += __shfl_xor(ax, 32, 64);
    ay += __shfl_xor(ay, 32, 64);
    if (slot == 0) {
        float dn = dis[wid];
        float sw = dn * dn;
        unsigned v = hw[(size_t)wid * 32 + c];
        ax += sw * bf_lo(v);
        ay += sw * bf_hi(v);
        float2 b = ((const float2*)bias)[c];
        float al = aslope[0];
        ax += b.x; ay += b.y;
        ax = (ax >= 0.f) ? ax : al * ax;
        ay = (ay >= 0.f) ? ay : al * ay;
        ((float2*)out)[(size_t)wid * 32 + c] = make_float2(ax, ay);
    }
}

// ---------------- launch ----------------

extern "C" void kernel_launch(void* const* d_in, const int* in_sizes, int n_in,
                              void* d_out, int out_size, void* d_ws, size_t ws_size,
                              hipStream_t stream) {
    const float* x  = (const float*)d_in[0];
    const int*   ei = (const int*)d_in[1];
    const int*   src = ei;
    const int*   dst = ei + N_EDGES;
    const float* W1 = (const float*)d_in[2];
    const float* b1 = (const float*)d_in[3];
    const float* W2 = (const float*)d_in[4];
    const float* b2 = (const float*)d_in[5];
    const float* a  = (const float*)d_in[6];
    float* out = (float*)d_out;

    char* ws = (char*)d_ws;
    size_t off = 0;
    auto alloc = [&](size_t bytes) -> void* {
        void* p = ws + off;
        off += (bytes + 255) & ~(size_t)255;
        return p;
    };
    int*      count     = (int*)alloc((size_t)N_NODES * 4);
    int*      row_start = (int*)alloc((size_t)(N_NODES + 1) * 4);
    int*      fill      = (int*)alloc((size_t)N_NODES * 4);
    float*    dis       = (float*)alloc((size_t)N_NODES * 4);
    int*      bsum      = (int*)alloc(512 * 4);
    uint2*    edge      = (uint2*)alloc((size_t)N_EDGES * 8);
    unsigned* hw1       = (unsigned*)alloc((size_t)N_NODES * 64 * 4);  // bf16 [N,128]
    unsigned* hbuf      = (unsigned*)alloc((size_t)N_NODES * 64 * 4);  // bf16 [N,128]
    unsigned* hw2       = (unsigned*)alloc((size_t)N_NODES * 32 * 4);  // bf16 [N,64]

    hipMemsetAsync(count, 0, (size_t)N_NODES * 4, stream);

    int gE = (N_EDGES + 255) / 256;   // 6250
    int gN = (N_NODES + 255) / 256;   // 391

    hist_k<<<gE, 256, 0, stream>>>(dst, count, N_EDGES);
    dis_k<<<gN, 256, 0, stream>>>(count, dis, N_NODES);
    scan_blocks_k<<<gN, 256, 0, stream>>>(count, row_start, bsum, N_NODES);
    scan_sums_k<<<1, 512, 0, stream>>>(bsum, gN);
    add_off_k<<<gN, 256, 0, stream>>>(row_start, fill, bsum, N_NODES, N_EDGES);
    scatter_k<<<gE, 256, 0, stream>>>(src, dst, dis, fill, edge, N_EDGES);

    int gG = (N_NODES + 127) / 128;   // 782
    int gA = (N_NODES + 3) / 4;       // 25000 (4 waves/block, 1 wave/node)

    gemm_k<128, false><<<gG, 256, 0, stream>>>(x, W1, hw1, N_NODES);
    agg1_k<<<gA, 256, 0, stream>>>(hw1, row_start, edge, dis, b1, a, hbuf, N_NODES);
    gemm_k<64, true><<<gG, 256, 0, stream>>>(hbuf, W2, hw2, N_NODES);
    agg2_k<<<gA, 256, 0, stream>>>(hw2, row_start, edge, dis, b2, a, out, N_NODES);
}

// Round 3
// 437.493 us; speedup vs baseline: 1.5616x; 1.3424x over previous
//
#include <hip/hip_runtime.h>

#define N_NODES 100000
#define N_EDGES 1600000

typedef short bf16x8 __attribute__((ext_vector_type(8)));
typedef float f32x4 __attribute__((ext_vector_type(4)));

// ---------------- bf16 helpers (storage only; math in f32) ----------------

__device__ __forceinline__ unsigned pack_bf16x2(float a, float b) {
    unsigned ua = __float_as_uint(a), ub = __float_as_uint(b);
    unsigned ra = (ua + 0x7fffu + ((ua >> 16) & 1u)) >> 16;   // RNE
    unsigned rb = (ub + 0x7fffu + ((ub >> 16) & 1u)) >> 16;
    return ra | (rb << 16);
}
__device__ __forceinline__ unsigned short bf16_rne(float f) {
    unsigned u = __float_as_uint(f);
    return (unsigned short)((u + 0x7fffu + ((u >> 16) & 1u)) >> 16);
}
__device__ __forceinline__ float bf_lo(unsigned v) { return __uint_as_float(v << 16); }
__device__ __forceinline__ float bf_hi(unsigned v) { return __uint_as_float(v & 0xffff0000u); }

// ---------------- CSR build ----------------

__global__ void hist_k(const int* __restrict__ dst, int* __restrict__ count, int E) {
    int e = blockIdx.x * 256 + threadIdx.x;
    if (e < E) atomicAdd(&count[dst[e]], 1);
}

__global__ void dis_k(const int* __restrict__ count, float* __restrict__ dis, int n) {
    int i = blockIdx.x * 256 + threadIdx.x;
    if (i < n) dis[i] = rsqrtf((float)(count[i] + 1));  // +1 self-loop
}

__global__ void scan_blocks_k(const int* __restrict__ count, int* __restrict__ row_start,
                              int* __restrict__ bsum, int n) {
    __shared__ int s[256];
    int tid = threadIdx.x;
    int i = blockIdx.x * 256 + tid;
    int v = (i < n) ? count[i] : 0;
    s[tid] = v; __syncthreads();
    for (int off = 1; off < 256; off <<= 1) {
        int t = 0;
        if (tid >= off) t = s[tid - off];
        __syncthreads();
        s[tid] += t;
        __syncthreads();
    }
    if (i < n) row_start[i] = s[tid] - v;
    if (tid == 255) bsum[blockIdx.x] = s[255];
}

__global__ void scan_sums_k(int* __restrict__ bsum, int nb) {
    __shared__ int s[512];
    int tid = threadIdx.x;
    int v = (tid < nb) ? bsum[tid] : 0;
    s[tid] = v; __syncthreads();
    for (int off = 1; off < 512; off <<= 1) {
        int t = 0;
        if (tid >= off) t = s[tid - off];
        __syncthreads();
        s[tid] += t;
        __syncthreads();
    }
    if (tid < nb) bsum[tid] = s[tid] - v;
}

__global__ void add_off_k(int* __restrict__ row_start, int* __restrict__ fill,
                          const int* __restrict__ bsum, int n, int E) {
    int i = blockIdx.x * 256 + threadIdx.x;
    if (i < n) {
        int r = row_start[i] + bsum[blockIdx.x];
        row_start[i] = r;
        fill[i] = r;
    }
    if (i == 0) row_start[n] = E;
}

__global__ void scatter_k(const int* __restrict__ src, const int* __restrict__ dst,
                          const float* __restrict__ dis, int* __restrict__ fill,
                          uint2* __restrict__ edge, int E) {
    int e = blockIdx.x * 256 + threadIdx.x;
    if (e < E) {
        int s = src[e], d = dst[e];
        int pos = atomicAdd(&fill[d], 1);
        edge[pos] = make_uint2((unsigned)s, __float_as_uint(dis[s] * dis[d]));
    }
}

// ---- W pre-transform: W[128][C] f32 -> Wt[C][128] bf16, 16B-granule XOR swizzle ----
// element (k, c) stored at Wt[c*128 + (g ^ (c&7))*8 + j], g = k>>3, j = k&7

__global__ void wt_k(const float* __restrict__ W, unsigned short* __restrict__ Wt, int C) {
    int t = blockIdx.x * 256 + threadIdx.x;
    if (t >= 128 * C) return;
    int k = t / C, c = t % C;
    int g = k >> 3, j = k & 7;
    Wt[c * 128 + ((g ^ (c & 7)) << 3) + j] = bf16_rne(W[t]);
}

// ---- MFMA GEMM: Y[nrows x OUTF](bf16) = X[nrows x 128] @ W[128 x OUTF] ----
// 128 rows/block; wave w owns rows [w*32, w*32+32) = 2 row-tiles of 16.
// A: row = lane&15, k = (lane>>4)*8 + j ; B: col = lane&15, same k ;
// D: col = lane&15, row = (lane>>4)*4 + reg.

template <int OUTF, bool INBF>
__global__ __launch_bounds__(256) void gemm_mfma_k(const void* __restrict__ Xv,
                                                   const unsigned short* __restrict__ Wt,
                                                   unsigned short* __restrict__ Y, int nrows) {
    constexpr int CT = OUTF / 16;
    __shared__ short lds_w[OUTF * 128];
    int tid = threadIdx.x;
    {   // stage pre-swizzled Wt linearly (conflict-free ds_write_b128)
        const uint4* srcp = (const uint4*)Wt;
        uint4* dstp = (uint4*)lds_w;
        for (int i = tid; i < OUTF * 16; i += 256) dstp[i] = srcp[i];
    }
    __syncthreads();
    int lane = tid & 63;
    int r16 = lane & 15, kq = lane >> 4;
    int rbase = blockIdx.x * 128 + (tid >> 6) * 32;
    f32x4 acc[2][CT] = {};
#pragma unroll
    for (int kk = 0; kk < 4; ++kk) {
        int k0 = kk * 32 + kq * 8;
        bf16x8 a[2];
#pragma unroll
        for (int rt = 0; rt < 2; ++rt) {
            int row = rbase + rt * 16 + r16;
            if (row < nrows) {
                if constexpr (INBF) {
                    a[rt] = *(const bf16x8*)((const unsigned short*)Xv + (size_t)row * 128 + k0);
                } else {
                    const float* xp = (const float*)Xv + (size_t)row * 128 + k0;
                    float4 f0 = *(const float4*)xp;
                    float4 f1 = *(const float4*)(xp + 4);
                    uint4 uu = make_uint4(pack_bf16x2(f0.x, f0.y), pack_bf16x2(f0.z, f0.w),
                                          pack_bf16x2(f1.x, f1.y), pack_bf16x2(f1.z, f1.w));
                    a[rt] = *(bf16x8*)&uu;
                }
            } else {
                bf16x8 z = {0, 0, 0, 0, 0, 0, 0, 0};
                a[rt] = z;
            }
        }
#pragma unroll
        for (int c = 0; c < CT; ++c) {
            int col = c * 16 + r16;
            int gp = (kk * 4 + kq) ^ (col & 7);
            bf16x8 b = *(const bf16x8*)&lds_w[col * 128 + gp * 8];
            acc[0][c] = __builtin_amdgcn_mfma_f32_16x16x32_bf16(a[0], b, acc[0][c], 0, 0, 0);
            acc[1][c] = __builtin_amdgcn_mfma_f32_16x16x32_bf16(a[1], b, acc[1][c], 0, 0, 0);
        }
    }
#pragma unroll
    for (int rt = 0; rt < 2; ++rt) {
#pragma unroll
        for (int c = 0; c < CT; ++c) {
#pragma unroll
            for (int r = 0; r < 4; ++r) {
                int row = rbase + rt * 16 + kq * 4 + r;
                if (row < nrows)
                    Y[(size_t)row * OUTF + c * 16 + r16] = bf16_rne(acc[rt][c][r]);
            }
        }
    }
}

// ---------------- Aggregation (fused bias + PReLU) ----------------

// Layer 1: 128 bf16 cols/row = 64 uints; 1 wave/node, 1 uint/lane. Output h in bf16.
__global__ void agg1_k(const unsigned* __restrict__ hw, const int* __restrict__ row_start,
                       const uint2* __restrict__ edge, const float* __restrict__ dis,
                       const float* __restrict__ bias, const float* __restrict__ aslope,
                       unsigned* __restrict__ out, int n) {
    int wid = (blockIdx.x * 256 + threadIdx.x) >> 6;
    int lane = threadIdx.x & 63;
    if (wid >= n) return;
    float ax = 0.f, ay = 0.f;
    int e0 = row_start[wid], e1 = row_start[wid + 1];
    for (int e = e0; e < e1; ++e) {
        uint2 ed = edge[e];
        float nr = __uint_as_float(ed.y);
        unsigned v = hw[(size_t)ed.x * 64 + lane];
        ax += nr * bf_lo(v);
        ay += nr * bf_hi(v);
    }
    float dn = dis[wid];
    float sw = dn * dn;
    unsigned v = hw[(size_t)wid * 64 + lane];
    ax += sw * bf_lo(v);
    ay += sw * bf_hi(v);
    float2 b = ((const float2*)bias)[lane];
    float al = aslope[0];
    ax += b.x; ay += b.y;
    ax = (ax >= 0.f) ? ax : al * ax;
    ay = (ay >= 0.f) ? ay : al * ay;
    out[(size_t)wid * 64 + lane] = pack_bf16x2(ax, ay);
}

// Layer 2: 64 bf16 cols/row = 32 uints; half-wave per edge (2 edges/iter), f32 output.
__global__ void agg2_k(const unsigned* __restrict__ hw, const int* __restrict__ row_start,
                       const uint2* __restrict__ edge, const float* __restrict__ dis,
                       const float* __restrict__ bias, const float* __restrict__ aslope,
                       float* __restrict__ out, int n) {
    int wid = (blockIdx.x * 256 + threadIdx.x) >> 6;
    int lane = threadIdx.x & 63;
    if (wid >= n) return;
    int slot = lane >> 5;
    int c = lane & 31;
    float ax = 0.f, ay = 0.f;
    int e0 = row_start[wid], e1 = row_start[wid + 1];
    for (int e = e0; e < e1; e += 2) {
        int ee = e + slot;
        if (ee < e1) {
            uint2 ed = edge[ee];
            float nr = __uint_as_float(ed.y);
            unsigned v = hw[(size_t)ed.x * 32 + c];
            ax += nr * bf_lo(v);
            ay += nr * bf_hi(v);
        }
    }
    ax += __shfl_xor(ax, 32, 64);
    ay += __shfl_xor(ay, 32, 64);
    if (slot == 0) {
        float dn = dis[wid];
        float sw = dn * dn;
        unsigned v = hw[(size_t)wid * 32 + c];
        ax += sw * bf_lo(v);
        ay += sw * bf_hi(v);
        float2 b = ((const float2*)bias)[c];
        float al = aslope[0];
        ax += b.x; ay += b.y;
        ax = (ax >= 0.f) ? ax : al * ax;
        ay = (ay >= 0.f) ? ay : al * ay;
        ((float2*)out)[(size_t)wid * 32 + c] = make_float2(ax, ay);
    }
}

// ---------------- launch ----------------

extern "C" void kernel_launch(void* const* d_in, const int* in_sizes, int n_in,
                              void* d_out, int out_size, void* d_ws, size_t ws_size,
                              hipStream_t stream) {
    const float* x  = (const float*)d_in[0];
    const int*   ei = (const int*)d_in[1];
    const int*   src = ei;
    const int*   dst = ei + N_EDGES;
    const float* W1 = (const float*)d_in[2];
    const float* b1 = (const float*)d_in[3];
    const float* W2 = (const float*)d_in[4];
    const float* b2 = (const float*)d_in[5];
    const float* a  = (const float*)d_in[6];
    float* out = (float*)d_out;

    char* ws = (char*)d_ws;
    size_t off = 0;
    auto alloc = [&](size_t bytes) -> void* {
        void* p = ws + off;
        off += (bytes + 255) & ~(size_t)255;
        return p;
    };
    int*            count     = (int*)alloc((size_t)N_NODES * 4);
    int*            row_start = (int*)alloc((size_t)(N_NODES + 1) * 4);
    int*            fill      = (int*)alloc((size_t)N_NODES * 4);
    float*          dis       = (float*)alloc((size_t)N_NODES * 4);
    int*            bsum      = (int*)alloc(512 * 4);
    uint2*          edge      = (uint2*)alloc((size_t)N_EDGES * 8);
    unsigned*       hw1       = (unsigned*)alloc((size_t)N_NODES * 64 * 4);  // bf16 [N,128]
    unsigned*       hbuf      = (unsigned*)alloc((size_t)N_NODES * 64 * 4);  // bf16 [N,128]
    unsigned*       hw2       = (unsigned*)alloc((size_t)N_NODES * 32 * 4);  // bf16 [N,64]
    unsigned short* Wt1       = (unsigned short*)alloc(128 * 128 * 2);
    unsigned short* Wt2       = (unsigned short*)alloc(64 * 128 * 2);

    hipMemsetAsync(count, 0, (size_t)N_NODES * 4, stream);

    int gE = (N_EDGES + 255) / 256;   // 6250
    int gN = (N_NODES + 255) / 256;   // 391

    wt_k<<<64, 256, 0, stream>>>(W1, Wt1, 128);
    wt_k<<<32, 256, 0, stream>>>(W2, Wt2, 64);

    hist_k<<<gE, 256, 0, stream>>>(dst, count, N_EDGES);
    dis_k<<<gN, 256, 0, stream>>>(count, dis, N_NODES);
    scan_blocks_k<<<gN, 256, 0, stream>>>(count, row_start, bsum, N_NODES);
    scan_sums_k<<<1, 512, 0, stream>>>(bsum, gN);
    add_off_k<<<gN, 256, 0, stream>>>(row_start, fill, bsum, N_NODES, N_EDGES);
    scatter_k<<<gE, 256, 0, stream>>>(src, dst, dis, fill, edge, N_EDGES);

    int gG = (N_NODES + 127) / 128;   // 782
    int gA = (N_NODES + 3) / 4;       // 25000 (4 waves/block, 1 wave/node)

    gemm_mfma_k<128, false><<<gG, 256, 0, stream>>>(x, Wt1, (unsigned short*)hw1, N_NODES);
    agg1_k<<<gA, 256, 0, stream>>>(hw1, row_start, edge, dis, b1, a, hbuf, N_NODES);
    gemm_mfma_k<64, true><<<gG, 256, 0, stream>>>(hbuf, Wt2, (unsigned short*)hw2, N_NODES);
    agg2_k<<<gA, 256, 0, stream>>>(hw2, row_start, edge, dis, b2, a, out, N_NODES);
}

// Round 4
// 342.435 us; speedup vs baseline: 1.9951x; 1.2776x over previous
//
#include <hip/hip_runtime.h>

#define N_NODES 100000
#define N_EDGES 1600000

typedef short bf16x8 __attribute__((ext_vector_type(8)));
typedef float f32x4 __attribute__((ext_vector_type(4)));

// ---------------- bf16 helpers (storage only; math in f32) ----------------

__device__ __forceinline__ unsigned pack_bf16x2(float a, float b) {
    unsigned ua = __float_as_uint(a), ub = __float_as_uint(b);
    unsigned ra = (ua + 0x7fffu + ((ua >> 16) & 1u)) >> 16;   // RNE
    unsigned rb = (ub + 0x7fffu + ((ub >> 16) & 1u)) >> 16;
    return ra | (rb << 16);
}
__device__ __forceinline__ unsigned short bf16_rne(float f) {
    unsigned u = __float_as_uint(f);
    return (unsigned short)((u + 0x7fffu + ((u >> 16) & 1u)) >> 16);
}
__device__ __forceinline__ float bf_lo(unsigned v) { return __uint_as_float(v << 16); }
__device__ __forceinline__ float bf_hi(unsigned v) { return __uint_as_float(v & 0xffff0000u); }

// ---------------- CSR build ----------------

__global__ void hist_k(const int* __restrict__ dst, int* __restrict__ count, int E) {
    int e = blockIdx.x * 256 + threadIdx.x;
    if (e < E) atomicAdd(&count[dst[e]], 1);
}

__global__ void dis_k(const int* __restrict__ count, float* __restrict__ dis, int n) {
    int i = blockIdx.x * 256 + threadIdx.x;
    if (i < n) dis[i] = rsqrtf((float)(count[i] + 1));  // +1 self-loop
}

__global__ void scan_blocks_k(const int* __restrict__ count, int* __restrict__ row_start,
                              int* __restrict__ bsum, int n) {
    __shared__ int s[256];
    int tid = threadIdx.x;
    int i = blockIdx.x * 256 + tid;
    int v = (i < n) ? count[i] : 0;
    s[tid] = v; __syncthreads();
    for (int off = 1; off < 256; off <<= 1) {
        int t = 0;
        if (tid >= off) t = s[tid - off];
        __syncthreads();
        s[tid] += t;
        __syncthreads();
    }
    if (i < n) row_start[i] = s[tid] - v;
    if (tid == 255) bsum[blockIdx.x] = s[255];
}

__global__ void scan_sums_k(int* __restrict__ bsum, int nb) {
    __shared__ int s[512];
    int tid = threadIdx.x;
    int v = (tid < nb) ? bsum[tid] : 0;
    s[tid] = v; __syncthreads();
    for (int off = 1; off < 512; off <<= 1) {
        int t = 0;
        if (tid >= off) t = s[tid - off];
        __syncthreads();
        s[tid] += t;
        __syncthreads();
    }
    if (tid < nb) bsum[tid] = s[tid] - v;
}

__global__ void add_off_k(int* __restrict__ row_start, int* __restrict__ fill,
                          const int* __restrict__ bsum, int n, int E) {
    int i = blockIdx.x * 256 + threadIdx.x;
    if (i < n) {
        int r = row_start[i] + bsum[blockIdx.x];
        row_start[i] = r;
        fill[i] = r;
    }
    if (i == 0) row_start[n] = E;
}

__global__ void scatter_k(const int* __restrict__ src, const int* __restrict__ dst,
                          const float* __restrict__ dis, int* __restrict__ fill,
                          uint2* __restrict__ edge, int E) {
    int e = blockIdx.x * 256 + threadIdx.x;
    if (e < E) {
        int s = src[e], d = dst[e];
        int pos = atomicAdd(&fill[d], 1);
        edge[pos] = make_uint2((unsigned)s, __float_as_uint(dis[s] * dis[d]));
    }
}

// ---- W pre-transform: W[128][C] f32 -> Wt[C][128] bf16, 16B-granule XOR swizzle ----

__global__ void wt_k(const float* __restrict__ W, unsigned short* __restrict__ Wt, int C) {
    int t = blockIdx.x * 256 + threadIdx.x;
    if (t >= 128 * C) return;
    int k = t / C, c = t % C;
    int g = k >> 3, j = k & 7;
    Wt[c * 128 + ((g ^ (c & 7)) << 3) + j] = bf16_rne(W[t]);
}

// ---- MFMA GEMM: Y[nrows x OUTF](bf16) = X[nrows x 128] @ W[128 x OUTF] ----

template <int OUTF, bool INBF>
__global__ __launch_bounds__(256) void gemm_mfma_k(const void* __restrict__ Xv,
                                                   const unsigned short* __restrict__ Wt,
                                                   unsigned short* __restrict__ Y, int nrows) {
    constexpr int CT = OUTF / 16;
    __shared__ short lds_w[OUTF * 128];
    int tid = threadIdx.x;
    {
        const uint4* srcp = (const uint4*)Wt;
        uint4* dstp = (uint4*)lds_w;
        for (int i = tid; i < OUTF * 16; i += 256) dstp[i] = srcp[i];
    }
    __syncthreads();
    int lane = tid & 63;
    int r16 = lane & 15, kq = lane >> 4;
    int rbase = blockIdx.x * 128 + (tid >> 6) * 32;
    f32x4 acc[2][CT] = {};
#pragma unroll
    for (int kk = 0; kk < 4; ++kk) {
        int k0 = kk * 32 + kq * 8;
        bf16x8 a[2];
#pragma unroll
        for (int rt = 0; rt < 2; ++rt) {
            int row = rbase + rt * 16 + r16;
            if (row < nrows) {
                if constexpr (INBF) {
                    a[rt] = *(const bf16x8*)((const unsigned short*)Xv + (size_t)row * 128 + k0);
                } else {
                    const float* xp = (const float*)Xv + (size_t)row * 128 + k0;
                    float4 f0 = *(const float4*)xp;
                    float4 f1 = *(const float4*)(xp + 4);
                    uint4 uu = make_uint4(pack_bf16x2(f0.x, f0.y), pack_bf16x2(f0.z, f0.w),
                                          pack_bf16x2(f1.x, f1.y), pack_bf16x2(f1.z, f1.w));
                    a[rt] = *(bf16x8*)&uu;
                }
            } else {
                bf16x8 z = {0, 0, 0, 0, 0, 0, 0, 0};
                a[rt] = z;
            }
        }
#pragma unroll
        for (int c = 0; c < CT; ++c) {
            int col = c * 16 + r16;
            int gp = (kk * 4 + kq) ^ (col & 7);
            bf16x8 b = *(const bf16x8*)&lds_w[col * 128 + gp * 8];
            acc[0][c] = __builtin_amdgcn_mfma_f32_16x16x32_bf16(a[0], b, acc[0][c], 0, 0, 0);
            acc[1][c] = __builtin_amdgcn_mfma_f32_16x16x32_bf16(a[1], b, acc[1][c], 0, 0, 0);
        }
    }
#pragma unroll
    for (int rt = 0; rt < 2; ++rt) {
#pragma unroll
        for (int c = 0; c < CT; ++c) {
#pragma unroll
            for (int r = 0; r < 4; ++r) {
                int row = rbase + rt * 16 + kq * 4 + r;
                if (row < nrows)
                    Y[(size_t)row * OUTF + c * 16 + r16] = bf16_rne(acc[rt][c][r]);
            }
        }
    }
}

// ---------------- Aggregation (fused bias + PReLU), unrolled for MLP ----------------

// Layer 1: 128 bf16 cols/row = 64 uints; 1 wave/node, 1 uint/lane, 8 edges in flight.
__global__ void agg1_k(const unsigned* __restrict__ hw, const int* __restrict__ row_start,
                       const uint2* __restrict__ edge, const float* __restrict__ dis,
                       const float* __restrict__ bias, const float* __restrict__ aslope,
                       unsigned* __restrict__ out, int n) {
    int wid = (blockIdx.x * 256 + threadIdx.x) >> 6;
    int lane = threadIdx.x & 63;
    if (wid >= n) return;
    float ax = 0.f, ay = 0.f;
    int e0 = row_start[wid], e1 = row_start[wid + 1];
    for (int e = e0; e < e1; e += 8) {
        uint2 ed[8];
        unsigned v[8];
#pragma unroll
        for (int i = 0; i < 8; ++i) {
            int ee = e + i;
            int ec = (ee < e1) ? ee : (e1 - 1);
            ed[i] = edge[ec];
        }
#pragma unroll
        for (int i = 0; i < 8; ++i) v[i] = hw[(size_t)ed[i].x * 64 + lane];
#pragma unroll
        for (int i = 0; i < 8; ++i) {
            float nr = (e + i < e1) ? __uint_as_float(ed[i].y) : 0.f;
            ax += nr * bf_lo(v[i]);
            ay += nr * bf_hi(v[i]);
        }
    }
    float dn = dis[wid];
    float sw = dn * dn;
    unsigned v = hw[(size_t)wid * 64 + lane];
    ax += sw * bf_lo(v);
    ay += sw * bf_hi(v);
    float2 b = ((const float2*)bias)[lane];
    float al = aslope[0];
    ax += b.x; ay += b.y;
    ax = (ax >= 0.f) ? ax : al * ax;
    ay = (ay >= 0.f) ? ay : al * ay;
    out[(size_t)wid * 64 + lane] = pack_bf16x2(ax, ay);
}

// Layer 2: 64 bf16 cols/row = 32 uints; half-wave per edge, 4 edges/slot in flight.
__global__ void agg2_k(const unsigned* __restrict__ hw, const int* __restrict__ row_start,
                       const uint2* __restrict__ edge, const float* __restrict__ dis,
                       const float* __restrict__ bias, const float* __restrict__ aslope,
                       float* __restrict__ out, int n) {
    int wid = (blockIdx.x * 256 + threadIdx.x) >> 6;
    int lane = threadIdx.x & 63;
    if (wid >= n) return;
    int slot = lane >> 5;
    int c = lane & 31;
    float ax = 0.f, ay = 0.f;
    int e0 = row_start[wid], e1 = row_start[wid + 1];
    for (int e = e0; e < e1; e += 8) {
        uint2 ed[4];
        unsigned v[4];
#pragma unroll
        for (int i = 0; i < 4; ++i) {
            int ee = e + 2 * i + slot;
            int ec = (ee < e1) ? ee : (e1 - 1);
            ed[i] = edge[ec];
        }
#pragma unroll
        for (int i = 0; i < 4; ++i) v[i] = hw[(size_t)ed[i].x * 32 + c];
#pragma unroll
        for (int i = 0; i < 4; ++i) {
            float nr = (e + 2 * i + slot < e1) ? __uint_as_float(ed[i].y) : 0.f;
            ax += nr * bf_lo(v[i]);
            ay += nr * bf_hi(v[i]);
        }
    }
    ax += __shfl_xor(ax, 32, 64);
    ay += __shfl_xor(ay, 32, 64);
    if (slot == 0) {
        float dn = dis[wid];
        float sw = dn * dn;
        unsigned v = hw[(size_t)wid * 32 + c];
        ax += sw * bf_lo(v);
        ay += sw * bf_hi(v);
        float2 b = ((const float2*)bias)[c];
        float al = aslope[0];
        ax += b.x; ay += b.y;
        ax = (ax >= 0.f) ? ax : al * ax;
        ay = (ay >= 0.f) ? ay : al * ay;
        ((float2*)out)[(size_t)wid * 32 + c] = make_float2(ax, ay);
    }
}

// ---------------- launch ----------------

extern "C" void kernel_launch(void* const* d_in, const int* in_sizes, int n_in,
                              void* d_out, int out_size, void* d_ws, size_t ws_size,
                              hipStream_t stream) {
    const float* x  = (const float*)d_in[0];
    const int*   ei = (const int*)d_in[1];
    const int*   src = ei;
    const int*   dst = ei + N_EDGES;
    const float* W1 = (const float*)d_in[2];
    const float* b1 = (const float*)d_in[3];
    const float* W2 = (const float*)d_in[4];
    const float* b2 = (const float*)d_in[5];
    const float* a  = (const float*)d_in[6];
    float* out = (float*)d_out;

    char* ws = (char*)d_ws;
    size_t off = 0;
    auto alloc = [&](size_t bytes) -> void* {
        void* p = ws + off;
        off += (bytes + 255) & ~(size_t)255;
        return p;
    };
    int*            count     = (int*)alloc((size_t)N_NODES * 4);
    int*            row_start = (int*)alloc((size_t)(N_NODES + 1) * 4);
    int*            fill      = (int*)alloc((size_t)N_NODES * 4);
    float*          dis       = (float*)alloc((size_t)N_NODES * 4);
    int*            bsum      = (int*)alloc(512 * 4);
    uint2*          edge      = (uint2*)alloc((size_t)N_EDGES * 8);
    unsigned*       hw1       = (unsigned*)alloc((size_t)N_NODES * 64 * 4);  // bf16 [N,128]
    unsigned*       hbuf      = (unsigned*)alloc((size_t)N_NODES * 64 * 4);  // bf16 [N,128]
    unsigned*       hw2       = (unsigned*)alloc((size_t)N_NODES * 32 * 4);  // bf16 [N,64]
    unsigned short* Wt1       = (unsigned short*)alloc(128 * 128 * 2);
    unsigned short* Wt2       = (unsigned short*)alloc(64 * 128 * 2);

    hipMemsetAsync(count, 0, (size_t)N_NODES * 4, stream);

    int gE = (N_EDGES + 255) / 256;   // 6250
    int gN = (N_NODES + 255) / 256;   // 391

    wt_k<<<64, 256, 0, stream>>>(W1, Wt1, 128);
    wt_k<<<32, 256, 0, stream>>>(W2, Wt2, 64);

    hist_k<<<gE, 256, 0, stream>>>(dst, count, N_EDGES);
    dis_k<<<gN, 256, 0, stream>>>(count, dis, N_NODES);
    scan_blocks_k<<<gN, 256, 0, stream>>>(count, row_start, bsum, N_NODES);
    scan_sums_k<<<1, 512, 0, stream>>>(bsum, gN);
    add_off_k<<<gN, 256, 0, stream>>>(row_start, fill, bsum, N_NODES, N_EDGES);
    scatter_k<<<gE, 256, 0, stream>>>(src, dst, dis, fill, edge, N_EDGES);

    int gG = (N_NODES + 127) / 128;   // 782
    int gA = (N_NODES + 3) / 4;       // 25000 (4 waves/block, 1 wave/node)

    gemm_mfma_k<128, false><<<gG, 256, 0, stream>>>(x, Wt1, (unsigned short*)hw1, N_NODES);
    agg1_k<<<gA, 256, 0, stream>>>(hw1, row_start, edge, dis, b1, a, hbuf, N_NODES);
    gemm_mfma_k<64, true><<<gG, 256, 0, stream>>>(hbuf, Wt2, (unsigned short*)hw2, N_NODES);
    agg2_k<<<gA, 256, 0, stream>>>(hw2, row_start, edge, dis, b2, a, out, N_NODES);
}

// Round 5
// 301.703 us; speedup vs baseline: 2.2645x; 1.1350x over previous
//
#include <hip/hip_runtime.h>

#define N_NODES 100000
#define N_EDGES 1600000
#define BSH 9                      // 512 nodes per bucket
#define NB  196                    // ceil(N_NODES / 512)
#define EPB 2048                   // edges per bin_k block

typedef short bf16x8 __attribute__((ext_vector_type(8)));
typedef float f32x4 __attribute__((ext_vector_type(4)));

// ---------------- bf16 helpers (storage only; math in f32) ----------------

__device__ __forceinline__ unsigned pack_bf16x2(float a, float b) {
    unsigned ua = __float_as_uint(a), ub = __float_as_uint(b);
    unsigned ra = (ua + 0x7fffu + ((ua >> 16) & 1u)) >> 16;   // RNE
    unsigned rb = (ub + 0x7fffu + ((ub >> 16) & 1u)) >> 16;
    return ra | (rb << 16);
}
__device__ __forceinline__ unsigned short bf16_rne(float f) {
    unsigned u = __float_as_uint(f);
    return (unsigned short)((u + 0x7fffu + ((u >> 16) & 1u)) >> 16);
}
__device__ __forceinline__ float bf_lo(unsigned v) { return __uint_as_float(v << 16); }
__device__ __forceinline__ float bf_hi(unsigned v) { return __uint_as_float(v & 0xffff0000u); }

// ---------------- CSR build ----------------

__global__ void hist_k(const int* __restrict__ dst, int* __restrict__ count, int E) {
    int e0 = blockIdx.x * 1024 + threadIdx.x;
#pragma unroll
    for (int i = 0; i < 4; ++i) {
        int e = e0 + i * 256;
        if (e < E) atomicAdd(&count[dst[e]], 1);
    }
}

__global__ void dis_k(const int* __restrict__ count, float* __restrict__ dis, int n) {
    int i = blockIdx.x * 256 + threadIdx.x;
    if (i < n) dis[i] = rsqrtf((float)(count[i] + 1));  // +1 self-loop
}

__global__ void scan_blocks_k(const int* __restrict__ count, int* __restrict__ row_start,
                              int* __restrict__ bsum, int n) {
    __shared__ int s[256];
    int tid = threadIdx.x;
    int i = blockIdx.x * 256 + tid;
    int v = (i < n) ? count[i] : 0;
    s[tid] = v; __syncthreads();
    for (int off = 1; off < 256; off <<= 1) {
        int t = 0;
        if (tid >= off) t = s[tid - off];
        __syncthreads();
        s[tid] += t;
        __syncthreads();
    }
    if (i < n) row_start[i] = s[tid] - v;
    if (tid == 255) bsum[blockIdx.x] = s[255];
}

__global__ void scan_sums_k(int* __restrict__ bsum, int nb) {
    __shared__ int s[512];
    int tid = threadIdx.x;
    int v = (tid < nb) ? bsum[tid] : 0;
    s[tid] = v; __syncthreads();
    for (int off = 1; off < 512; off <<= 1) {
        int t = 0;
        if (tid >= off) t = s[tid - off];
        __syncthreads();
        s[tid] += t;
        __syncthreads();
    }
    if (tid < nb) bsum[tid] = s[tid] - v;
}

__global__ void add_off_k(int* __restrict__ row_start, const int* __restrict__ bsum,
                          int n, int E) {
    int i = blockIdx.x * 256 + threadIdx.x;
    if (i < n) row_start[i] += bsum[blockIdx.x];
    if (i == 0) row_start[n] = E;
}

__global__ void cursor_init_k(const int* __restrict__ row_start, int* __restrict__ cursor) {
    int b = threadIdx.x;
    if (b < NB) cursor[b] = row_start[b << BSH];
}

// Phase 1: bin edges by dst bucket; payload = (dst_low9 << 17) | src (N < 2^17).
__global__ __launch_bounds__(256) void bin_k(const int* __restrict__ src,
                                             const int* __restrict__ dst,
                                             int* __restrict__ cursor,
                                             unsigned* __restrict__ binned, int E) {
    __shared__ int lhist[256];
    __shared__ int lbase[256];
    int tid = threadIdx.x;
    lhist[tid] = 0;
    __syncthreads();
    int e0 = blockIdx.x * EPB;
    int bkt[8], rnk[8], dl[8];
#pragma unroll
    for (int i = 0; i < 8; ++i) {
        int e = e0 + tid + i * 256;
        if (e < E) {
            int d = dst[e];
            bkt[i] = d >> BSH;
            dl[i] = d & ((1 << BSH) - 1);
            rnk[i] = atomicAdd(&lhist[bkt[i]], 1);
        } else {
            bkt[i] = -1;
        }
    }
    __syncthreads();
    int cnt = lhist[tid];
    if (tid < NB && cnt > 0) lbase[tid] = atomicAdd(&cursor[tid], cnt);
    __syncthreads();
#pragma unroll
    for (int i = 0; i < 8; ++i) {
        if (bkt[i] >= 0) {
            int e = e0 + tid + i * 256;
            binned[lbase[bkt[i]] + rnk[i]] = ((unsigned)dl[i] << 17) | (unsigned)src[e];
        }
    }
}

// Phase 2: place binned edges at exact CSR slots (bucket-local writes).
__global__ __launch_bounds__(256) void csr_k(const unsigned* __restrict__ binned,
                                             const int* __restrict__ row_start,
                                             const float* __restrict__ dis,
                                             uint2* __restrict__ edge, int n) {
    __shared__ int lfill[1 << BSH];
    int b = blockIdx.x, tid = threadIdx.x;
    int nbase = b << BSH;
    for (int j = tid; j < (1 << BSH); j += 256) {
        int node = nbase + j;
        lfill[j] = (node < n) ? row_start[node] : 0;
    }
    __syncthreads();
    int rs = row_start[nbase];
    int nend = nbase + (1 << BSH);
    int re = row_start[(nend < n) ? nend : n];
    for (int i = rs + tid; i < re; i += 256) {
        unsigned u = binned[i];
        int s = u & 0x1FFFFu;
        int dl = u >> 17;
        int pos = atomicAdd(&lfill[dl], 1);
        edge[pos] = make_uint2((unsigned)s, __float_as_uint(dis[s] * dis[nbase + dl]));
    }
}

// ---- W pre-transform: W[128][C] f32 -> Wt[C][128] bf16, 16B-granule XOR swizzle ----

__global__ void wt_k(const float* __restrict__ W, unsigned short* __restrict__ Wt, int C) {
    int t = blockIdx.x * 256 + threadIdx.x;
    if (t >= 128 * C) return;
    int k = t / C, c = t % C;
    int g = k >> 3, j = k & 7;
    Wt[c * 128 + ((g ^ (c & 7)) << 3) + j] = bf16_rne(W[t]);
}

// ---- MFMA GEMM: Y[nrows x OUTF](bf16) = X[nrows x 128] @ W[128 x OUTF] ----

template <int OUTF, bool INBF>
__global__ __launch_bounds__(256) void gemm_mfma_k(const void* __restrict__ Xv,
                                                   const unsigned short* __restrict__ Wt,
                                                   unsigned short* __restrict__ Y, int nrows) {
    constexpr int CT = OUTF / 16;
    __shared__ short lds_w[OUTF * 128];
    int tid = threadIdx.x;
    {
        const uint4* srcp = (const uint4*)Wt;
        uint4* dstp = (uint4*)lds_w;
        for (int i = tid; i < OUTF * 16; i += 256) dstp[i] = srcp[i];
    }
    __syncthreads();
    int lane = tid & 63;
    int r16 = lane & 15, kq = lane >> 4;
    int rbase = blockIdx.x * 128 + (tid >> 6) * 32;
    f32x4 acc[2][CT] = {};
#pragma unroll
    for (int kk = 0; kk < 4; ++kk) {
        int k0 = kk * 32 + kq * 8;
        bf16x8 a[2];
#pragma unroll
        for (int rt = 0; rt < 2; ++rt) {
            int row = rbase + rt * 16 + r16;
            if (row < nrows) {
                if constexpr (INBF) {
                    a[rt] = *(const bf16x8*)((const unsigned short*)Xv + (size_t)row * 128 + k0);
                } else {
                    const float* xp = (const float*)Xv + (size_t)row * 128 + k0;
                    float4 f0 = *(const float4*)xp;
                    float4 f1 = *(const float4*)(xp + 4);
                    uint4 uu = make_uint4(pack_bf16x2(f0.x, f0.y), pack_bf16x2(f0.z, f0.w),
                                          pack_bf16x2(f1.x, f1.y), pack_bf16x2(f1.z, f1.w));
                    a[rt] = *(bf16x8*)&uu;
                }
            } else {
                bf16x8 z = {0, 0, 0, 0, 0, 0, 0, 0};
                a[rt] = z;
            }
        }
#pragma unroll
        for (int c = 0; c < CT; ++c) {
            int col = c * 16 + r16;
            int gp = (kk * 4 + kq) ^ (col & 7);
            bf16x8 b = *(const bf16x8*)&lds_w[col * 128 + gp * 8];
            acc[0][c] = __builtin_amdgcn_mfma_f32_16x16x32_bf16(a[0], b, acc[0][c], 0, 0, 0);
            acc[1][c] = __builtin_amdgcn_mfma_f32_16x16x32_bf16(a[1], b, acc[1][c], 0, 0, 0);
        }
    }
#pragma unroll
    for (int rt = 0; rt < 2; ++rt) {
#pragma unroll
        for (int c = 0; c < CT; ++c) {
#pragma unroll
            for (int r = 0; r < 4; ++r) {
                int row = rbase + rt * 16 + kq * 4 + r;
                if (row < nrows)
                    Y[(size_t)row * OUTF + c * 16 + r16] = bf16_rne(acc[rt][c][r]);
            }
        }
    }
}

// ---------------- Aggregation (fused bias + PReLU), unrolled for MLP ----------------

__global__ void agg1_k(const unsigned* __restrict__ hw, const int* __restrict__ row_start,
                       const uint2* __restrict__ edge, const float* __restrict__ dis,
                       const float* __restrict__ bias, const float* __restrict__ aslope,
                       unsigned* __restrict__ out, int n) {
    int wid = (blockIdx.x * 256 + threadIdx.x) >> 6;
    int lane = threadIdx.x & 63;
    if (wid >= n) return;
    float ax = 0.f, ay = 0.f;
    int e0 = row_start[wid], e1 = row_start[wid + 1];
    for (int e = e0; e < e1; e += 8) {
        uint2 ed[8];
        unsigned v[8];
#pragma unroll
        for (int i = 0; i < 8; ++i) {
            int ee = e + i;
            int ec = (ee < e1) ? ee : (e1 - 1);
            ed[i] = edge[ec];
        }
#pragma unroll
        for (int i = 0; i < 8; ++i) v[i] = hw[(size_t)ed[i].x * 64 + lane];
#pragma unroll
        for (int i = 0; i < 8; ++i) {
            float nr = (e + i < e1) ? __uint_as_float(ed[i].y) : 0.f;
            ax += nr * bf_lo(v[i]);
            ay += nr * bf_hi(v[i]);
        }
    }
    float dn = dis[wid];
    float sw = dn * dn;
    unsigned v = hw[(size_t)wid * 64 + lane];
    ax += sw * bf_lo(v);
    ay += sw * bf_hi(v);
    float2 b = ((const float2*)bias)[lane];
    float al = aslope[0];
    ax += b.x; ay += b.y;
    ax = (ax >= 0.f) ? ax : al * ax;
    ay = (ay >= 0.f) ? ay : al * ay;
    out[(size_t)wid * 64 + lane] = pack_bf16x2(ax, ay);
}

__global__ void agg2_k(const unsigned* __restrict__ hw, const int* __restrict__ row_start,
                       const uint2* __restrict__ edge, const float* __restrict__ dis,
                       const float* __restrict__ bias, const float* __restrict__ aslope,
                       float* __restrict__ out, int n) {
    int wid = (blockIdx.x * 256 + threadIdx.x) >> 6;
    int lane = threadIdx.x & 63;
    if (wid >= n) return;
    int slot = lane >> 5;
    int c = lane & 31;
    float ax = 0.f, ay = 0.f;
    int e0 = row_start[wid], e1 = row_start[wid + 1];
    for (int e = e0; e < e1; e += 8) {
        uint2 ed[4];
        unsigned v[4];
#pragma unroll
        for (int i = 0; i < 4; ++i) {
            int ee = e + 2 * i + slot;
            int ec = (ee < e1) ? ee : (e1 - 1);
            ed[i] = edge[ec];
        }
#pragma unroll
        for (int i = 0; i < 4; ++i) v[i] = hw[(size_t)ed[i].x * 32 + c];
#pragma unroll
        for (int i = 0; i < 4; ++i) {
            float nr = (e + 2 * i + slot < e1) ? __uint_as_float(ed[i].y) : 0.f;
            ax += nr * bf_lo(v[i]);
            ay += nr * bf_hi(v[i]);
        }
    }
    ax += __shfl_xor(ax, 32, 64);
    ay += __shfl_xor(ay, 32, 64);
    if (slot == 0) {
        float dn = dis[wid];
        float sw = dn * dn;
        unsigned v = hw[(size_t)wid * 32 + c];
        ax += sw * bf_lo(v);
        ay += sw * bf_hi(v);
        float2 b = ((const float2*)bias)[c];
        float al = aslope[0];
        ax += b.x; ay += b.y;
        ax = (ax >= 0.f) ? ax : al * ax;
        ay = (ay >= 0.f) ? ay : al * ay;
        ((float2*)out)[(size_t)wid * 32 + c] = make_float2(ax, ay);
    }
}

// ---------------- launch ----------------

extern "C" void kernel_launch(void* const* d_in, const int* in_sizes, int n_in,
                              void* d_out, int out_size, void* d_ws, size_t ws_size,
                              hipStream_t stream) {
    const float* x  = (const float*)d_in[0];
    const int*   ei = (const int*)d_in[1];
    const int*   src = ei;
    const int*   dst = ei + N_EDGES;
    const float* W1 = (const float*)d_in[2];
    const float* b1 = (const float*)d_in[3];
    const float* W2 = (const float*)d_in[4];
    const float* b2 = (const float*)d_in[5];
    const float* a  = (const float*)d_in[6];
    float* out = (float*)d_out;

    char* ws = (char*)d_ws;
    size_t off = 0;
    auto alloc = [&](size_t bytes) -> void* {
        void* p = ws + off;
        off += (bytes + 255) & ~(size_t)255;
        return p;
    };
    int*            count     = (int*)alloc((size_t)N_NODES * 4);
    int*            row_start = (int*)alloc((size_t)(N_NODES + 1) * 4);
    float*          dis       = (float*)alloc((size_t)N_NODES * 4);
    int*            bsum      = (int*)alloc(512 * 4);
    int*            cursor    = (int*)alloc(NB * 4);
    unsigned*       binned    = (unsigned*)alloc((size_t)N_EDGES * 4);
    uint2*          edge      = (uint2*)alloc((size_t)N_EDGES * 8);
    unsigned*       hw1       = (unsigned*)alloc((size_t)N_NODES * 64 * 4);  // bf16 [N,128]
    unsigned*       hbuf      = (unsigned*)alloc((size_t)N_NODES * 64 * 4);  // bf16 [N,128]
    unsigned*       hw2       = (unsigned*)alloc((size_t)N_NODES * 32 * 4);  // bf16 [N,64]
    unsigned short* Wt1       = (unsigned short*)alloc(128 * 128 * 2);
    unsigned short* Wt2       = (unsigned short*)alloc(64 * 128 * 2);

    hipMemsetAsync(count, 0, (size_t)N_NODES * 4, stream);

    int gN = (N_NODES + 255) / 256;          // 391
    int gH = (N_EDGES + 1023) / 1024;        // 1563
    int gB = (N_EDGES + EPB - 1) / EPB;      // 782

    wt_k<<<64, 256, 0, stream>>>(W1, Wt1, 128);
    wt_k<<<32, 256, 0, stream>>>(W2, Wt2, 64);

    hist_k<<<gH, 256, 0, stream>>>(dst, count, N_EDGES);
    dis_k<<<gN, 256, 0, stream>>>(count, dis, N_NODES);
    scan_blocks_k<<<gN, 256, 0, stream>>>(count, row_start, bsum, N_NODES);
    scan_sums_k<<<1, 512, 0, stream>>>(bsum, gN);
    add_off_k<<<gN, 256, 0, stream>>>(row_start, bsum, N_NODES, N_EDGES);
    cursor_init_k<<<1, 256, 0, stream>>>(row_start, cursor);
    bin_k<<<gB, 256, 0, stream>>>(src, dst, cursor, binned, N_EDGES);
    csr_k<<<NB, 256, 0, stream>>>(binned, row_start, dis, edge, N_NODES);

    int gG = (N_NODES + 127) / 128;   // 782
    int gA = (N_NODES + 3) / 4;       // 25000 (4 waves/block, 1 wave/node)

    gemm_mfma_k<128, false><<<gG, 256, 0, stream>>>(x, Wt1, (unsigned short*)hw1, N_NODES);
    agg1_k<<<gA, 256, 0, stream>>>(hw1, row_start, edge, dis, b1, a, hbuf, N_NODES);
    gemm_mfma_k<64, true><<<gG, 256, 0, stream>>>(hbuf, Wt2, (unsigned short*)hw2, N_NODES);
    agg2_k<<<gA, 256, 0, stream>>>(hw2, row_start, edge, dis, b2, a, out, N_NODES);
}

// Round 6
// 277.896 us; speedup vs baseline: 2.4585x; 1.0857x over previous
//
#include <hip/hip_runtime.h>

#define N_NODES 100000
#define N_EDGES 1600000
#define BSH 9                      // 512 nodes per bucket
#define NB  196                    // ceil(N_NODES / 512)
#define EPB 2048                   // edges per bin_k block

typedef short bf16x8 __attribute__((ext_vector_type(8)));
typedef float f32x4 __attribute__((ext_vector_type(4)));

// ---------------- bf16 helpers (storage only; math in f32) ----------------

__device__ __forceinline__ unsigned pack_bf16x2(float a, float b) {
    unsigned ua = __float_as_uint(a), ub = __float_as_uint(b);
    unsigned ra = (ua + 0x7fffu + ((ua >> 16) & 1u)) >> 16;   // RNE
    unsigned rb = (ub + 0x7fffu + ((ub >> 16) & 1u)) >> 16;
    return ra | (rb << 16);
}
__device__ __forceinline__ unsigned short bf16_rne(float f) {
    unsigned u = __float_as_uint(f);
    return (unsigned short)((u + 0x7fffu + ((u >> 16) & 1u)) >> 16);
}
__device__ __forceinline__ float bf_lo(unsigned v) { return __uint_as_float(v << 16); }
__device__ __forceinline__ float bf_hi(unsigned v) { return __uint_as_float(v & 0xffff0000u); }

// ---------------- CSR build ----------------

__global__ void hist_k(const int* __restrict__ dst, int* __restrict__ count, int E) {
    int e0 = blockIdx.x * 1024 + threadIdx.x;
#pragma unroll
    for (int i = 0; i < 4; ++i) {
        int e = e0 + i * 256;
        if (e < E) atomicAdd(&count[dst[e]], 1);
    }
}

__global__ void dis_k(const int* __restrict__ count, float* __restrict__ dis, int n) {
    int i = blockIdx.x * 256 + threadIdx.x;
    if (i < n) dis[i] = rsqrtf((float)(count[i] + 1));  // +1 self-loop
}

__global__ void scan_blocks_k(const int* __restrict__ count, int* __restrict__ row_start,
                              int* __restrict__ bsum, int n) {
    __shared__ int s[256];
    int tid = threadIdx.x;
    int i = blockIdx.x * 256 + tid;
    int v = (i < n) ? count[i] : 0;
    s[tid] = v; __syncthreads();
    for (int off = 1; off < 256; off <<= 1) {
        int t = 0;
        if (tid >= off) t = s[tid - off];
        __syncthreads();
        s[tid] += t;
        __syncthreads();
    }
    if (i < n) row_start[i] = s[tid] - v;
    if (tid == 255) bsum[blockIdx.x] = s[255];
}

__global__ void scan_sums_k(int* __restrict__ bsum, int nb) {
    __shared__ int s[512];
    int tid = threadIdx.x;
    int v = (tid < nb) ? bsum[tid] : 0;
    s[tid] = v; __syncthreads();
    for (int off = 1; off < 512; off <<= 1) {
        int t = 0;
        if (tid >= off) t = s[tid - off];
        __syncthreads();
        s[tid] += t;
        __syncthreads();
    }
    if (tid < nb) bsum[tid] = s[tid] - v;
}

__global__ void add_off_k(int* __restrict__ row_start, const int* __restrict__ bsum,
                          int n, int E) {
    int i = blockIdx.x * 256 + threadIdx.x;
    if (i < n) row_start[i] += bsum[blockIdx.x];
    if (i == 0) row_start[n] = E;
}

__global__ void cursor_init_k(const int* __restrict__ row_start, int* __restrict__ cursor) {
    int b = threadIdx.x;
    if (b < NB) cursor[b] = row_start[b << BSH];
}

// Phase 1: bin edges by dst bucket; payload = (dst_low9 << 17) | src (N < 2^17).
__global__ __launch_bounds__(256) void bin_k(const int* __restrict__ src,
                                             const int* __restrict__ dst,
                                             int* __restrict__ cursor,
                                             unsigned* __restrict__ binned, int E) {
    __shared__ int lhist[256];
    __shared__ int lbase[256];
    int tid = threadIdx.x;
    lhist[tid] = 0;
    __syncthreads();
    int e0 = blockIdx.x * EPB;
    int bkt[8], rnk[8], dl[8];
#pragma unroll
    for (int i = 0; i < 8; ++i) {
        int e = e0 + tid + i * 256;
        if (e < E) {
            int d = dst[e];
            bkt[i] = d >> BSH;
            dl[i] = d & ((1 << BSH) - 1);
            rnk[i] = atomicAdd(&lhist[bkt[i]], 1);
        } else {
            bkt[i] = -1;
        }
    }
    __syncthreads();
    int cnt = lhist[tid];
    if (tid < NB && cnt > 0) lbase[tid] = atomicAdd(&cursor[tid], cnt);
    __syncthreads();
#pragma unroll
    for (int i = 0; i < 8; ++i) {
        if (bkt[i] >= 0) {
            int e = e0 + tid + i * 256;
            binned[lbase[bkt[i]] + rnk[i]] = ((unsigned)dl[i] << 17) | (unsigned)src[e];
        }
    }
}

// Phase 2: place binned edges at exact CSR slots (bucket-local writes).
__global__ __launch_bounds__(256) void csr_k(const unsigned* __restrict__ binned,
                                             const int* __restrict__ row_start,
                                             const float* __restrict__ dis,
                                             uint2* __restrict__ edge, int n) {
    __shared__ int lfill[1 << BSH];
    int b = blockIdx.x, tid = threadIdx.x;
    int nbase = b << BSH;
    for (int j = tid; j < (1 << BSH); j += 256) {
        int node = nbase + j;
        lfill[j] = (node < n) ? row_start[node] : 0;
    }
    __syncthreads();
    int rs = row_start[nbase];
    int nend = nbase + (1 << BSH);
    int re = row_start[(nend < n) ? nend : n];
    for (int i = rs + tid; i < re; i += 256) {
        unsigned u = binned[i];
        int s = u & 0x1FFFFu;
        int dl = u >> 17;
        int pos = atomicAdd(&lfill[dl], 1);
        edge[pos] = make_uint2((unsigned)s, __float_as_uint(dis[s] * dis[nbase + dl]));
    }
}

// ---- W pre-transform: W[128][C] f32 -> Wt[C][128] bf16, 16B-granule XOR swizzle ----

__global__ void wt_k(const float* __restrict__ W, unsigned short* __restrict__ Wt, int C) {
    int t = blockIdx.x * 256 + threadIdx.x;
    if (t >= 128 * C) return;
    int k = t / C, c = t % C;
    int g = k >> 3, j = k & 7;
    Wt[c * 128 + ((g ^ (c & 7)) << 3) + j] = bf16_rne(W[t]);
}

// ---- MFMA GEMM: Y[nrows x OUTF](bf16) = X[nrows x 128] @ W[128 x OUTF] ----

template <int OUTF, bool INBF>
__global__ __launch_bounds__(256) void gemm_mfma_k(const void* __restrict__ Xv,
                                                   const unsigned short* __restrict__ Wt,
                                                   unsigned short* __restrict__ Y, int nrows) {
    constexpr int CT = OUTF / 16;
    __shared__ short lds_w[OUTF * 128];
    int tid = threadIdx.x;
    {
        const uint4* srcp = (const uint4*)Wt;
        uint4* dstp = (uint4*)lds_w;
        for (int i = tid; i < OUTF * 16; i += 256) dstp[i] = srcp[i];
    }
    __syncthreads();
    int lane = tid & 63;
    int r16 = lane & 15, kq = lane >> 4;
    int rbase = blockIdx.x * 128 + (tid >> 6) * 32;
    f32x4 acc[2][CT] = {};
#pragma unroll
    for (int kk = 0; kk < 4; ++kk) {
        int k0 = kk * 32 + kq * 8;
        bf16x8 a[2];
#pragma unroll
        for (int rt = 0; rt < 2; ++rt) {
            int row = rbase + rt * 16 + r16;
            if (row < nrows) {
                if constexpr (INBF) {
                    a[rt] = *(const bf16x8*)((const unsigned short*)Xv + (size_t)row * 128 + k0);
                } else {
                    const float* xp = (const float*)Xv + (size_t)row * 128 + k0;
                    float4 f0 = *(const float4*)xp;
                    float4 f1 = *(const float4*)(xp + 4);
                    uint4 uu = make_uint4(pack_bf16x2(f0.x, f0.y), pack_bf16x2(f0.z, f0.w),
                                          pack_bf16x2(f1.x, f1.y), pack_bf16x2(f1.z, f1.w));
                    a[rt] = *(bf16x8*)&uu;
                }
            } else {
                bf16x8 z = {0, 0, 0, 0, 0, 0, 0, 0};
                a[rt] = z;
            }
        }
#pragma unroll
        for (int c = 0; c < CT; ++c) {
            int col = c * 16 + r16;
            int gp = (kk * 4 + kq) ^ (col & 7);
            bf16x8 b = *(const bf16x8*)&lds_w[col * 128 + gp * 8];
            acc[0][c] = __builtin_amdgcn_mfma_f32_16x16x32_bf16(a[0], b, acc[0][c], 0, 0, 0);
            acc[1][c] = __builtin_amdgcn_mfma_f32_16x16x32_bf16(a[1], b, acc[1][c], 0, 0, 0);
        }
    }
#pragma unroll
    for (int rt = 0; rt < 2; ++rt) {
#pragma unroll
        for (int c = 0; c < CT; ++c) {
#pragma unroll
            for (int r = 0; r < 4; ++r) {
                int row = rbase + rt * 16 + kq * 4 + r;
                if (row < nrows)
                    Y[(size_t)row * OUTF + c * 16 + r16] = bf16_rne(acc[rt][c][r]);
            }
        }
    }
}

// ---------------- Aggregation (fused bias + PReLU), 16-lane edge groups ----------------

// Layer 1: row = 128 bf16 = 256 B. 4 edges/wave concurrently (16 lanes x uint4 each),
// unroll 4 -> 16 rows in flight. Cross-group combine via 2 shfl_xor levels.
__global__ void agg1_k(const unsigned* __restrict__ hw, const int* __restrict__ row_start,
                       const uint2* __restrict__ edge, const float* __restrict__ dis,
                       const float* __restrict__ bias, const float* __restrict__ aslope,
                       unsigned* __restrict__ out, int n) {
    int wid = (blockIdx.x * 256 + threadIdx.x) >> 6;
    int lane = threadIdx.x & 63;
    if (wid >= n) return;
    int g = lane >> 4;        // edge slot 0..3
    int li = lane & 15;       // 16B granule (cols li*8 .. li*8+7)
    float acc[8] = {};
    int e0 = row_start[wid], e1 = row_start[wid + 1];
    for (int e = e0; e < e1; e += 16) {
        uint2 ed[4];
        uint4 v[4];
#pragma unroll
        for (int u = 0; u < 4; ++u) {
            int ee = e + u * 4 + g;
            int ec = (ee < e1) ? ee : (e1 - 1);
            ed[u] = edge[ec];
        }
#pragma unroll
        for (int u = 0; u < 4; ++u)
            v[u] = *(const uint4*)(hw + (size_t)ed[u].x * 64 + li * 4);
#pragma unroll
        for (int u = 0; u < 4; ++u) {
            float nr = (e + u * 4 + g < e1) ? __uint_as_float(ed[u].y) : 0.f;
            acc[0] += nr * bf_lo(v[u].x); acc[1] += nr * bf_hi(v[u].x);
            acc[2] += nr * bf_lo(v[u].y); acc[3] += nr * bf_hi(v[u].y);
            acc[4] += nr * bf_lo(v[u].z); acc[5] += nr * bf_hi(v[u].z);
            acc[6] += nr * bf_lo(v[u].w); acc[7] += nr * bf_hi(v[u].w);
        }
    }
#pragma unroll
    for (int j = 0; j < 8; ++j) {
        acc[j] += __shfl_xor(acc[j], 16, 64);
        acc[j] += __shfl_xor(acc[j], 32, 64);
    }
    if (g == 0) {
        float dn = dis[wid];
        float sw = dn * dn;
        uint4 v = *(const uint4*)(hw + (size_t)wid * 64 + li * 4);
        acc[0] += sw * bf_lo(v.x); acc[1] += sw * bf_hi(v.x);
        acc[2] += sw * bf_lo(v.y); acc[3] += sw * bf_hi(v.y);
        acc[4] += sw * bf_lo(v.z); acc[5] += sw * bf_hi(v.z);
        acc[6] += sw * bf_lo(v.w); acc[7] += sw * bf_hi(v.w);
        float4 b0 = ((const float4*)bias)[li * 2];
        float4 b1 = ((const float4*)bias)[li * 2 + 1];
        float al = aslope[0];
        float r[8] = {acc[0] + b0.x, acc[1] + b0.y, acc[2] + b0.z, acc[3] + b0.w,
                      acc[4] + b1.x, acc[5] + b1.y, acc[6] + b1.z, acc[7] + b1.w};
#pragma unroll
        for (int j = 0; j < 8; ++j) r[j] = (r[j] >= 0.f) ? r[j] : al * r[j];
        uint4 o = make_uint4(pack_bf16x2(r[0], r[1]), pack_bf16x2(r[2], r[3]),
                             pack_bf16x2(r[4], r[5]), pack_bf16x2(r[6], r[7]));
        *(uint4*)(out + (size_t)wid * 64 + li * 4) = o;
    }
}

// Layer 2: row = 64 bf16 = 128 B. 4 edges/wave (16 lanes x uint2), unroll 4; f32 output.
__global__ void agg2_k(const unsigned* __restrict__ hw, const int* __restrict__ row_start,
                       const uint2* __restrict__ edge, const float* __restrict__ dis,
                       const float* __restrict__ bias, const float* __restrict__ aslope,
                       float* __restrict__ out, int n) {
    int wid = (blockIdx.x * 256 + threadIdx.x) >> 6;
    int lane = threadIdx.x & 63;
    if (wid >= n) return;
    int g = lane >> 4;        // edge slot 0..3
    int li = lane & 15;       // 8B granule (cols li*4 .. li*4+3)
    float acc[4] = {};
    int e0 = row_start[wid], e1 = row_start[wid + 1];
    for (int e = e0; e < e1; e += 16) {
        uint2 ed[4];
        uint2 v[4];
#pragma unroll
        for (int u = 0; u < 4; ++u) {
            int ee = e + u * 4 + g;
            int ec = (ee < e1) ? ee : (e1 - 1);
            ed[u] = edge[ec];
        }
#pragma unroll
        for (int u = 0; u < 4; ++u)
            v[u] = *(const uint2*)(hw + (size_t)ed[u].x * 32 + li * 2);
#pragma unroll
        for (int u = 0; u < 4; ++u) {
            float nr = (e + u * 4 + g < e1) ? __uint_as_float(ed[u].y) : 0.f;
            acc[0] += nr * bf_lo(v[u].x); acc[1] += nr * bf_hi(v[u].x);
            acc[2] += nr * bf_lo(v[u].y); acc[3] += nr * bf_hi(v[u].y);
        }
    }
#pragma unroll
    for (int j = 0; j < 4; ++j) {
        acc[j] += __shfl_xor(acc[j], 16, 64);
        acc[j] += __shfl_xor(acc[j], 32, 64);
    }
    if (g == 0) {
        float dn = dis[wid];
        float sw = dn * dn;
        uint2 v = *(const uint2*)(hw + (size_t)wid * 32 + li * 2);
        acc[0] += sw * bf_lo(v.x); acc[1] += sw * bf_hi(v.x);
        acc[2] += sw * bf_lo(v.y); acc[3] += sw * bf_hi(v.y);
        float4 b = ((const float4*)bias)[li];
        float al = aslope[0];
        float r[4] = {acc[0] + b.x, acc[1] + b.y, acc[2] + b.z, acc[3] + b.w};
#pragma unroll
        for (int j = 0; j < 4; ++j) r[j] = (r[j] >= 0.f) ? r[j] : al * r[j];
        *(float4*)(out + (size_t)wid * 64 + li * 4) = make_float4(r[0], r[1], r[2], r[3]);
    }
}

// ---------------- launch ----------------

extern "C" void kernel_launch(void* const* d_in, const int* in_sizes, int n_in,
                              void* d_out, int out_size, void* d_ws, size_t ws_size,
                              hipStream_t stream) {
    const float* x  = (const float*)d_in[0];
    const int*   ei = (const int*)d_in[1];
    const int*   src = ei;
    const int*   dst = ei + N_EDGES;
    const float* W1 = (const float*)d_in[2];
    const float* b1 = (const float*)d_in[3];
    const float* W2 = (const float*)d_in[4];
    const float* b2 = (const float*)d_in[5];
    const float* a  = (const float*)d_in[6];
    float* out = (float*)d_out;

    char* ws = (char*)d_ws;
    size_t off = 0;
    auto alloc = [&](size_t bytes) -> void* {
        void* p = ws + off;
        off += (bytes + 255) & ~(size_t)255;
        return p;
    };
    int*            count     = (int*)alloc((size_t)N_NODES * 4);
    int*            row_start = (int*)alloc((size_t)(N_NODES + 1) * 4);
    float*          dis       = (float*)alloc((size_t)N_NODES * 4);
    int*            bsum      = (int*)alloc(512 * 4);
    int*            cursor    = (int*)alloc(NB * 4);
    unsigned*       binned    = (unsigned*)alloc((size_t)N_EDGES * 4);
    uint2*          edge      = (uint2*)alloc((size_t)N_EDGES * 8);
    unsigned*       hw1       = (unsigned*)alloc((size_t)N_NODES * 64 * 4);  // bf16 [N,128]
    unsigned*       hbuf      = (unsigned*)alloc((size_t)N_NODES * 64 * 4);  // bf16 [N,128]
    unsigned*       hw2       = (unsigned*)alloc((size_t)N_NODES * 32 * 4);  // bf16 [N,64]
    unsigned short* Wt1       = (unsigned short*)alloc(128 * 128 * 2);
    unsigned short* Wt2       = (unsigned short*)alloc(64 * 128 * 2);

    hipMemsetAsync(count, 0, (size_t)N_NODES * 4, stream);

    int gN = (N_NODES + 255) / 256;          // 391
    int gH = (N_EDGES + 1023) / 1024;        // 1563
    int gB = (N_EDGES + EPB - 1) / EPB;      // 782

    wt_k<<<64, 256, 0, stream>>>(W1, Wt1, 128);
    wt_k<<<32, 256, 0, stream>>>(W2, Wt2, 64);

    hist_k<<<gH, 256, 0, stream>>>(dst, count, N_EDGES);
    dis_k<<<gN, 256, 0, stream>>>(count, dis, N_NODES);
    scan_blocks_k<<<gN, 256, 0, stream>>>(count, row_start, bsum, N_NODES);
    scan_sums_k<<<1, 512, 0, stream>>>(bsum, gN);
    add_off_k<<<gN, 256, 0, stream>>>(row_start, bsum, N_NODES, N_EDGES);
    cursor_init_k<<<1, 256, 0, stream>>>(row_start, cursor);
    bin_k<<<gB, 256, 0, stream>>>(src, dst, cursor, binned, N_EDGES);
    csr_k<<<NB, 256, 0, stream>>>(binned, row_start, dis, edge, N_NODES);

    int gG = (N_NODES + 127) / 128;   // 782
    int gA = (N_NODES + 3) / 4;       // 25000 (4 waves/block, 1 wave/node)

    gemm_mfma_k<128, false><<<gG, 256, 0, stream>>>(x, Wt1, (unsigned short*)hw1, N_NODES);
    agg1_k<<<gA, 256, 0, stream>>>(hw1, row_start, edge, dis, b1, a, hbuf, N_NODES);
    gemm_mfma_k<64, true><<<gG, 256, 0, stream>>>(hbuf, Wt2, (unsigned short*)hw2, N_NODES);
    agg2_k<<<gA, 256, 0, stream>>>(hw2, row_start, edge, dis, b2, a, out, N_NODES);
}

// Round 7
// 212.528 us; speedup vs baseline: 3.2146x; 1.3076x over previous
//
#include <hip/hip_runtime.h>

#define N_NODES 100000
#define N_EDGES 1600000
#define BSH 9                      // 512 nodes per bucket
#define NB  196                    // ceil(N_NODES / 512)
#define EPB 2048                   // edges per bin_k block
#define CAPSH 14                   // 16384 binned slots per bucket (avg fill ~8163)

typedef short bf16x8 __attribute__((ext_vector_type(8)));
typedef float f32x4 __attribute__((ext_vector_type(4)));

// ---------------- bf16 helpers (storage only; math in f32) ----------------

__device__ __forceinline__ unsigned pack_bf16x2(float a, float b) {
    unsigned ua = __float_as_uint(a), ub = __float_as_uint(b);
    unsigned ra = (ua + 0x7fffu + ((ua >> 16) & 1u)) >> 16;   // RNE
    unsigned rb = (ub + 0x7fffu + ((ub >> 16) & 1u)) >> 16;
    return ra | (rb << 16);
}
__device__ __forceinline__ unsigned short bf16_rne(float f) {
    unsigned u = __float_as_uint(f);
    return (unsigned short)((u + 0x7fffu + ((u >> 16) & 1u)) >> 16);
}
__device__ __forceinline__ float bf_lo(unsigned v) { return __uint_as_float(v << 16); }
__device__ __forceinline__ float bf_hi(unsigned v) { return __uint_as_float(v & 0xffff0000u); }

// ---------------- CSR build (histogram-free counting sort) ----------------

__global__ void cursor_init_k(int* __restrict__ cursor) {
    int b = threadIdx.x;
    if (b < NB) cursor[b] = b << CAPSH;
}

// Phase 1: bin edges by dst bucket into fixed-capacity runs.
// payload = (dst_low9 << 17) | src   (N < 2^17)
__global__ __launch_bounds__(256) void bin_k(const int* __restrict__ src,
                                             const int* __restrict__ dst,
                                             int* __restrict__ cursor,
                                             unsigned* __restrict__ binned, int E) {
    __shared__ int lhist[256];
    __shared__ int lbase[256];
    int tid = threadIdx.x;
    lhist[tid] = 0;
    __syncthreads();
    int e0 = blockIdx.x * EPB;
    int bkt[8], rnk[8], dl[8];
#pragma unroll
    for (int i = 0; i < 8; ++i) {
        int e = e0 + tid + i * 256;
        if (e < E) {
            int d = dst[e];
            bkt[i] = d >> BSH;
            dl[i] = d & ((1 << BSH) - 1);
            rnk[i] = atomicAdd(&lhist[bkt[i]], 1);
        } else {
            bkt[i] = -1;
        }
    }
    __syncthreads();
    int cnt = lhist[tid];
    if (tid < NB && cnt > 0) lbase[tid] = atomicAdd(&cursor[tid], cnt);
    __syncthreads();
#pragma unroll
    for (int i = 0; i < 8; ++i) {
        if (bkt[i] >= 0) {
            int e = e0 + tid + i * 256;
            int p = lbase[bkt[i]] + rnk[i];
            if (p < ((bkt[i] + 1) << CAPSH))   // capacity guard (never hits for this input)
                binned[p] = ((unsigned)dl[i] << 17) | (unsigned)src[e];
        }
    }
}

// Bucket totals -> exclusive scan -> global bucket base offsets.
__global__ void bucket_scan_k(const int* __restrict__ cursor, int* __restrict__ bucket_base) {
    __shared__ int s[256];
    int tid = threadIdx.x;
    int v = (tid < NB) ? (cursor[tid] - (tid << CAPSH)) : 0;
    s[tid] = v; __syncthreads();
    for (int off = 1; off < 256; off <<= 1) {
        int t = 0;
        if (tid >= off) t = s[tid - off];
        __syncthreads();
        s[tid] += t;
        __syncthreads();
    }
    if (tid < NB) bucket_base[tid] = s[tid] - v;
}

// Per-bucket: count degrees in LDS, local scan -> row_start, dis = rsqrt(deg+1).
__global__ __launch_bounds__(256) void deg_dis_k(const unsigned* __restrict__ binned,
                                                 const int* __restrict__ cursor,
                                                 const int* __restrict__ bucket_base,
                                                 int* __restrict__ row_start,
                                                 float* __restrict__ dis, int n, int E) {
    __shared__ int lcnt[1 << BSH];
    __shared__ int ls[256];
    int b = blockIdx.x, tid = threadIdx.x;
    for (int j = tid; j < (1 << BSH); j += 256) lcnt[j] = 0;
    __syncthreads();
    int base = b << CAPSH;
    int total = cursor[b] - base;
    for (int i = tid; i < total; i += 256)
        atomicAdd(&lcnt[binned[base + i] >> 17], 1);
    __syncthreads();
    int v0 = lcnt[2 * tid], v1 = lcnt[2 * tid + 1];
    int sv = v0 + v1;
    ls[tid] = sv;
    __syncthreads();
    for (int off = 1; off < 256; off <<= 1) {
        int t = 0;
        if (tid >= off) t = ls[tid - off];
        __syncthreads();
        ls[tid] += t;
        __syncthreads();
    }
    int pre = ls[tid] - sv;   // exclusive prefix over node pairs
    int nbase = b << BSH;
    int bb = bucket_base[b];
    int node0 = nbase + 2 * tid, node1 = node0 + 1;
    if (node0 < n) {
        row_start[node0] = bb + pre;
        dis[node0] = rsqrtf((float)(v0 + 1));
    }
    if (node1 < n) {
        row_start[node1] = bb + pre + v0;
        dis[node1] = rsqrtf((float)(v1 + 1));
    }
    if (b == NB - 1 && tid == 255) row_start[n] = E;
}

// Phase 2: place binned edges at exact CSR slots (bucket-local writes).
__global__ __launch_bounds__(256) void csr_k(const unsigned* __restrict__ binned,
                                             const int* __restrict__ cursor,
                                             const int* __restrict__ row_start,
                                             const float* __restrict__ dis,
                                             uint2* __restrict__ edge, int n) {
    __shared__ int lfill[1 << BSH];
    int b = blockIdx.x, tid = threadIdx.x;
    int nbase = b << BSH;
    for (int j = tid; j < (1 << BSH); j += 256) {
        int node = nbase + j;
        lfill[j] = (node < n) ? row_start[node] : 0;
    }
    __syncthreads();
    int base = b << CAPSH;
    int total = cursor[b] - base;
    for (int i = base + tid; i < base + total; i += 256) {
        unsigned u = binned[i];
        int s = u & 0x1FFFFu;
        int dl = u >> 17;
        int pos = atomicAdd(&lfill[dl], 1);
        edge[pos] = make_uint2((unsigned)s, __float_as_uint(dis[s] * dis[nbase + dl]));
    }
}

// ---- W pre-transform: W[128][C] f32 -> Wt[C][128] bf16, 16B-granule XOR swizzle ----

__global__ void wt_k(const float* __restrict__ W, unsigned short* __restrict__ Wt, int C) {
    int t = blockIdx.x * 256 + threadIdx.x;
    if (t >= 128 * C) return;
    int k = t / C, c = t % C;
    int g = k >> 3, j = k & 7;
    Wt[c * 128 + ((g ^ (c & 7)) << 3) + j] = bf16_rne(W[t]);
}

// ---- MFMA GEMM: Y[nrows x OUTF](bf16) = X[nrows x 128] @ W[128 x OUTF] ----

template <int OUTF, bool INBF>
__global__ __launch_bounds__(256) void gemm_mfma_k(const void* __restrict__ Xv,
                                                   const unsigned short* __restrict__ Wt,
                                                   unsigned short* __restrict__ Y, int nrows) {
    constexpr int CT = OUTF / 16;
    __shared__ short lds_w[OUTF * 128];
    int tid = threadIdx.x;
    {
        const uint4* srcp = (const uint4*)Wt;
        uint4* dstp = (uint4*)lds_w;
        for (int i = tid; i < OUTF * 16; i += 256) dstp[i] = srcp[i];
    }
    __syncthreads();
    int lane = tid & 63;
    int r16 = lane & 15, kq = lane >> 4;
    int rbase = blockIdx.x * 128 + (tid >> 6) * 32;
    f32x4 acc[2][CT] = {};
#pragma unroll
    for (int kk = 0; kk < 4; ++kk) {
        int k0 = kk * 32 + kq * 8;
        bf16x8 a[2];
#pragma unroll
        for (int rt = 0; rt < 2; ++rt) {
            int row = rbase + rt * 16 + r16;
            if (row < nrows) {
                if constexpr (INBF) {
                    a[rt] = *(const bf16x8*)((const unsigned short*)Xv + (size_t)row * 128 + k0);
                } else {
                    const float* xp = (const float*)Xv + (size_t)row * 128 + k0;
                    float4 f0 = *(const float4*)xp;
                    float4 f1 = *(const float4*)(xp + 4);
                    uint4 uu = make_uint4(pack_bf16x2(f0.x, f0.y), pack_bf16x2(f0.z, f0.w),
                                          pack_bf16x2(f1.x, f1.y), pack_bf16x2(f1.z, f1.w));
                    a[rt] = *(bf16x8*)&uu;
                }
            } else {
                bf16x8 z = {0, 0, 0, 0, 0, 0, 0, 0};
                a[rt] = z;
            }
        }
#pragma unroll
        for (int c = 0; c < CT; ++c) {
            int col = c * 16 + r16;
            int gp = (kk * 4 + kq) ^ (col & 7);
            bf16x8 b = *(const bf16x8*)&lds_w[col * 128 + gp * 8];
            acc[0][c] = __builtin_amdgcn_mfma_f32_16x16x32_bf16(a[0], b, acc[0][c], 0, 0, 0);
            acc[1][c] = __builtin_amdgcn_mfma_f32_16x16x32_bf16(a[1], b, acc[1][c], 0, 0, 0);
        }
    }
#pragma unroll
    for (int rt = 0; rt < 2; ++rt) {
#pragma unroll
        for (int c = 0; c < CT; ++c) {
#pragma unroll
            for (int r = 0; r < 4; ++r) {
                int row = rbase + rt * 16 + kq * 4 + r;
                if (row < nrows)
                    Y[(size_t)row * OUTF + c * 16 + r16] = bf16_rne(acc[rt][c][r]);
            }
        }
    }
}

// ---------------- Aggregation (fused bias + PReLU), 16-lane edge groups ----------------

__global__ void agg1_k(const unsigned* __restrict__ hw, const int* __restrict__ row_start,
                       const uint2* __restrict__ edge, const float* __restrict__ dis,
                       const float* __restrict__ bias, const float* __restrict__ aslope,
                       unsigned* __restrict__ out, int n) {
    int wid = (blockIdx.x * 256 + threadIdx.x) >> 6;
    int lane = threadIdx.x & 63;
    if (wid >= n) return;
    int g = lane >> 4;        // edge slot 0..3
    int li = lane & 15;       // 16B granule (cols li*8 .. li*8+7)
    float acc[8] = {};
    int e0 = row_start[wid], e1 = row_start[wid + 1];
    for (int e = e0; e < e1; e += 16) {
        uint2 ed[4];
        uint4 v[4];
#pragma unroll
        for (int u = 0; u < 4; ++u) {
            int ee = e + u * 4 + g;
            int ec = (ee < e1) ? ee : (e1 - 1);
            ed[u] = edge[ec];
        }
#pragma unroll
        for (int u = 0; u < 4; ++u)
            v[u] = *(const uint4*)(hw + (size_t)ed[u].x * 64 + li * 4);
#pragma unroll
        for (int u = 0; u < 4; ++u) {
            float nr = (e + u * 4 + g < e1) ? __uint_as_float(ed[u].y) : 0.f;
            acc[0] += nr * bf_lo(v[u].x); acc[1] += nr * bf_hi(v[u].x);
            acc[2] += nr * bf_lo(v[u].y); acc[3] += nr * bf_hi(v[u].y);
            acc[4] += nr * bf_lo(v[u].z); acc[5] += nr * bf_hi(v[u].z);
            acc[6] += nr * bf_lo(v[u].w); acc[7] += nr * bf_hi(v[u].w);
        }
    }
#pragma unroll
    for (int j = 0; j < 8; ++j) {
        acc[j] += __shfl_xor(acc[j], 16, 64);
        acc[j] += __shfl_xor(acc[j], 32, 64);
    }
    if (g == 0) {
        float dn = dis[wid];
        float sw = dn * dn;
        uint4 v = *(const uint4*)(hw + (size_t)wid * 64 + li * 4);
        acc[0] += sw * bf_lo(v.x); acc[1] += sw * bf_hi(v.x);
        acc[2] += sw * bf_lo(v.y); acc[3] += sw * bf_hi(v.y);
        acc[4] += sw * bf_lo(v.z); acc[5] += sw * bf_hi(v.z);
        acc[6] += sw * bf_lo(v.w); acc[7] += sw * bf_hi(v.w);
        float4 b0 = ((const float4*)bias)[li * 2];
        float4 b1 = ((const float4*)bias)[li * 2 + 1];
        float al = aslope[0];
        float r[8] = {acc[0] + b0.x, acc[1] + b0.y, acc[2] + b0.z, acc[3] + b0.w,
                      acc[4] + b1.x, acc[5] + b1.y, acc[6] + b1.z, acc[7] + b1.w};
#pragma unroll
        for (int j = 0; j < 8; ++j) r[j] = (r[j] >= 0.f) ? r[j] : al * r[j];
        uint4 o = make_uint4(pack_bf16x2(r[0], r[1]), pack_bf16x2(r[2], r[3]),
                             pack_bf16x2(r[4], r[5]), pack_bf16x2(r[6], r[7]));
        *(uint4*)(out + (size_t)wid * 64 + li * 4) = o;
    }
}

__global__ void agg2_k(const unsigned* __restrict__ hw, const int* __restrict__ row_start,
                       const uint2* __restrict__ edge, const float* __restrict__ dis,
                       const float* __restrict__ bias, const float* __restrict__ aslope,
                       float* __restrict__ out, int n) {
    int wid = (blockIdx.x * 256 + threadIdx.x) >> 6;
    int lane = threadIdx.x & 63;
    if (wid >= n) return;
    int g = lane >> 4;        // edge slot 0..3
    int li = lane & 15;       // 8B granule (cols li*4 .. li*4+3)
    float acc[4] = {};
    int e0 = row_start[wid], e1 = row_start[wid + 1];
    for (int e = e0; e < e1; e += 16) {
        uint2 ed[4];
        uint2 v[4];
#pragma unroll
        for (int u = 0; u < 4; ++u) {
            int ee = e + u * 4 + g;
            int ec = (ee < e1) ? ee : (e1 - 1);
            ed[u] = edge[ec];
        }
#pragma unroll
        for (int u = 0; u < 4; ++u)
            v[u] = *(const uint2*)(hw + (size_t)ed[u].x * 32 + li * 2);
#pragma unroll
        for (int u = 0; u < 4; ++u) {
            float nr = (e + u * 4 + g < e1) ? __uint_as_float(ed[u].y) : 0.f;
            acc[0] += nr * bf_lo(v[u].x); acc[1] += nr * bf_hi(v[u].x);
            acc[2] += nr * bf_lo(v[u].y); acc[3] += nr * bf_hi(v[u].y);
        }
    }
#pragma unroll
    for (int j = 0; j < 4; ++j) {
        acc[j] += __shfl_xor(acc[j], 16, 64);
        acc[j] += __shfl_xor(acc[j], 32, 64);
    }
    if (g == 0) {
        float dn = dis[wid];
        float sw = dn * dn;
        uint2 v = *(const uint2*)(hw + (size_t)wid * 32 + li * 2);
        acc[0] += sw * bf_lo(v.x); acc[1] += sw * bf_hi(v.x);
        acc[2] += sw * bf_lo(v.y); acc[3] += sw * bf_hi(v.y);
        float4 b = ((const float4*)bias)[li];
        float al = aslope[0];
        float r[4] = {acc[0] + b.x, acc[1] + b.y, acc[2] + b.z, acc[3] + b.w};
#pragma unroll
        for (int j = 0; j < 4; ++j) r[j] = (r[j] >= 0.f) ? r[j] : al * r[j];
        *(float4*)(out + (size_t)wid * 64 + li * 4) = make_float4(r[0], r[1], r[2], r[3]);
    }
}

// ---------------- launch ----------------

extern "C" void kernel_launch(void* const* d_in, const int* in_sizes, int n_in,
                              void* d_out, int out_size, void* d_ws, size_t ws_size,
                              hipStream_t stream) {
    const float* x  = (const float*)d_in[0];
    const int*   ei = (const int*)d_in[1];
    const int*   src = ei;
    const int*   dst = ei + N_EDGES;
    const float* W1 = (const float*)d_in[2];
    const float* b1 = (const float*)d_in[3];
    const float* W2 = (const float*)d_in[4];
    const float* b2 = (const float*)d_in[5];
    const float* a  = (const float*)d_in[6];
    float* out = (float*)d_out;

    char* ws = (char*)d_ws;
    size_t off = 0;
    auto alloc = [&](size_t bytes) -> void* {
        void* p = ws + off;
        off += (bytes + 255) & ~(size_t)255;
        return p;
    };
    int*            row_start = (int*)alloc((size_t)(N_NODES + 1) * 4);
    float*          dis       = (float*)alloc((size_t)N_NODES * 4);
    int*            cursor    = (int*)alloc(NB * 4);
    int*            bbase     = (int*)alloc(NB * 4);
    unsigned*       binned    = (unsigned*)alloc((size_t)NB * (1 << CAPSH) * 4);  // 12.8 MB
    uint2*          edge      = (uint2*)alloc((size_t)N_EDGES * 8);
    unsigned*       hw1       = (unsigned*)alloc((size_t)N_NODES * 64 * 4);  // bf16 [N,128]
    unsigned*       hbuf      = (unsigned*)alloc((size_t)N_NODES * 64 * 4);  // bf16 [N,128]
    unsigned*       hw2       = (unsigned*)alloc((size_t)N_NODES * 32 * 4);  // bf16 [N,64]
    unsigned short* Wt1       = (unsigned short*)alloc(128 * 128 * 2);
    unsigned short* Wt2       = (unsigned short*)alloc(64 * 128 * 2);

    int gB = (N_EDGES + EPB - 1) / EPB;      // 782

    wt_k<<<64, 256, 0, stream>>>(W1, Wt1, 128);
    wt_k<<<32, 256, 0, stream>>>(W2, Wt2, 64);

    cursor_init_k<<<1, 256, 0, stream>>>(cursor);
    bin_k<<<gB, 256, 0, stream>>>(src, dst, cursor, binned, N_EDGES);
    bucket_scan_k<<<1, 256, 0, stream>>>(cursor, bbase);
    deg_dis_k<<<NB, 256, 0, stream>>>(binned, cursor, bbase, row_start, dis, N_NODES, N_EDGES);
    csr_k<<<NB, 256, 0, stream>>>(binned, cursor, row_start, dis, edge, N_NODES);

    int gG = (N_NODES + 127) / 128;   // 782
    int gA = (N_NODES + 3) / 4;       // 25000 (4 waves/block, 1 wave/node)

    gemm_mfma_k<128, false><<<gG, 256, 0, stream>>>(x, Wt1, (unsigned short*)hw1, N_NODES);
    agg1_k<<<gA, 256, 0, stream>>>(hw1, row_start, edge, dis, b1, a, hbuf, N_NODES);
    gemm_mfma_k<64, true><<<gG, 256, 0, stream>>>(hbuf, Wt2, (unsigned short*)hw2, N_NODES);
    agg2_k<<<gA, 256, 0, stream>>>(hw2, row_start, edge, dis, b2, a, out, N_NODES);
}

// Round 8
// 207.616 us; speedup vs baseline: 3.2907x; 1.0237x over previous
//
#include <hip/hip_runtime.h>

#define N_NODES 100000
#define N_EDGES 1600000
#define BSH 9                      // 512 nodes per bucket
#define NB  196                    // ceil(N_NODES / 512)
#define EPB 4096                   // edges per bin_k block
#define CAPSH 14                   // 16384 binned slots per bucket (avg fill ~8163)

typedef short bf16x8 __attribute__((ext_vector_type(8)));
typedef float f32x4 __attribute__((ext_vector_type(4)));
typedef float f32x2 __attribute__((ext_vector_type(2)));

// ---------------- bf16 helpers (storage only; math in f32) ----------------

__device__ __forceinline__ unsigned pack_bf16x2(float a, float b) {
    unsigned ua = __float_as_uint(a), ub = __float_as_uint(b);
    unsigned ra = (ua + 0x7fffu + ((ua >> 16) & 1u)) >> 16;   // RNE
    unsigned rb = (ub + 0x7fffu + ((ub >> 16) & 1u)) >> 16;
    return ra | (rb << 16);
}
__device__ __forceinline__ unsigned short bf16_rne(float f) {
    unsigned u = __float_as_uint(f);
    return (unsigned short)((u + 0x7fffu + ((u >> 16) & 1u)) >> 16);
}
__device__ __forceinline__ float bf_lo(unsigned v) { return __uint_as_float(v << 16); }
__device__ __forceinline__ float bf_hi(unsigned v) { return __uint_as_float(v & 0xffff0000u); }
__device__ __forceinline__ f32x2 unpk(unsigned u) {
    f32x2 r;
    r.x = __uint_as_float(u << 16);
    r.y = __uint_as_float(u & 0xffff0000u);
    return r;
}

// ---------------- CSR build (histogram-free counting sort) ----------------

__global__ void cursor_init_k(int* __restrict__ cursor) {
    int b = threadIdx.x;
    if (b < NB) cursor[b] = b << CAPSH;
}

// Phase 1: bin edges by dst bucket into fixed-capacity runs (two-pass per block:
// LDS histogram -> one global allocation per bucket -> place via LDS cursors).
// payload = (dst_low9 << 17) | src   (N < 2^17)
__global__ __launch_bounds__(256) void bin_k(const int* __restrict__ src,
                                             const int* __restrict__ dst,
                                             int* __restrict__ cursor,
                                             unsigned* __restrict__ binned, int E) {
    __shared__ int lhist[256];
    __shared__ int lcur[256];
    int tid = threadIdx.x;
    lhist[tid] = 0;
    __syncthreads();
    int e0 = blockIdx.x * EPB;
#pragma unroll
    for (int i = 0; i < EPB / 256; ++i) {
        int e = e0 + i * 256 + tid;
        if (e < E) atomicAdd(&lhist[dst[e] >> BSH], 1);
    }
    __syncthreads();
    {
        int c = lhist[tid];
        lcur[tid] = (tid < NB && c > 0) ? atomicAdd(&cursor[tid], c) : 0;
    }
    __syncthreads();
#pragma unroll
    for (int i = 0; i < EPB / 256; ++i) {
        int e = e0 + i * 256 + tid;
        if (e < E) {
            int d = dst[e];
            int b = d >> BSH;
            int pos = atomicAdd(&lcur[b], 1);
            if (pos < ((b + 1) << CAPSH))   // capacity guard (never hits for this input)
                binned[pos] = ((unsigned)(d & ((1 << BSH) - 1)) << 17) | (unsigned)src[e];
        }
    }
}

// Bucket totals -> exclusive scan -> global bucket base offsets.
__global__ void bucket_scan_k(const int* __restrict__ cursor, int* __restrict__ bucket_base) {
    __shared__ int s[256];
    int tid = threadIdx.x;
    int v = (tid < NB) ? (cursor[tid] - (tid << CAPSH)) : 0;
    s[tid] = v; __syncthreads();
    for (int off = 1; off < 256; off <<= 1) {
        int t = 0;
        if (tid >= off) t = s[tid - off];
        __syncthreads();
        s[tid] += t;
        __syncthreads();
    }
    if (tid < NB) bucket_base[tid] = s[tid] - v;
}

// Per-bucket: count degrees in LDS, local scan -> row_start, dis = rsqrt(deg+1).
__global__ __launch_bounds__(256) void deg_dis_k(const unsigned* __restrict__ binned,
                                                 const int* __restrict__ cursor,
                                                 const int* __restrict__ bucket_base,
                                                 int* __restrict__ row_start,
                                                 float* __restrict__ dis, int n, int E) {
    __shared__ int lcnt[1 << BSH];
    __shared__ int ls[256];
    int b = blockIdx.x, tid = threadIdx.x;
    for (int j = tid; j < (1 << BSH); j += 256) lcnt[j] = 0;
    __syncthreads();
    int base = b << CAPSH;
    int total = cursor[b] - base;
    for (int i = tid; i < total; i += 256)
        atomicAdd(&lcnt[binned[base + i] >> 17], 1);
    __syncthreads();
    int v0 = lcnt[2 * tid], v1 = lcnt[2 * tid + 1];
    int sv = v0 + v1;
    ls[tid] = sv;
    __syncthreads();
    for (int off = 1; off < 256; off <<= 1) {
        int t = 0;
        if (tid >= off) t = ls[tid - off];
        __syncthreads();
        ls[tid] += t;
        __syncthreads();
    }
    int pre = ls[tid] - sv;   // exclusive prefix over node pairs
    int nbase = b << BSH;
    int bb = bucket_base[b];
    int node0 = nbase + 2 * tid, node1 = node0 + 1;
    if (node0 < n) {
        row_start[node0] = bb + pre;
        dis[node0] = rsqrtf((float)(v0 + 1));
    }
    if (node1 < n) {
        row_start[node1] = bb + pre + v0;
        dis[node1] = rsqrtf((float)(v1 + 1));
    }
    if (b == NB - 1 && tid == 255) row_start[n] = E;
}

// Phase 2: place binned edges at exact CSR slots (bucket-local writes).
__global__ __launch_bounds__(256) void csr_k(const unsigned* __restrict__ binned,
                                             const int* __restrict__ cursor,
                                             const int* __restrict__ row_start,
                                             const float* __restrict__ dis,
                                             uint2* __restrict__ edge, int n) {
    __shared__ int lfill[1 << BSH];
    int b = blockIdx.x, tid = threadIdx.x;
    int nbase = b << BSH;
    for (int j = tid; j < (1 << BSH); j += 256) {
        int node = nbase + j;
        lfill[j] = (node < n) ? row_start[node] : 0;
    }
    __syncthreads();
    int base = b << CAPSH;
    int total = cursor[b] - base;
    for (int i = base + tid; i < base + total; i += 256) {
        unsigned u = binned[i];
        int s = u & 0x1FFFFu;
        int dl = u >> 17;
        int pos = atomicAdd(&lfill[dl], 1);
        edge[pos] = make_uint2((unsigned)s, __float_as_uint(dis[s] * dis[nbase + dl]));
    }
}

// ---- W pre-transform: W[128][C] f32 -> Wt[C][128] bf16, 16B-granule XOR swizzle ----

__global__ void wt_k(const float* __restrict__ W, unsigned short* __restrict__ Wt, int C) {
    int t = blockIdx.x * 256 + threadIdx.x;
    if (t >= 128 * C) return;
    int k = t / C, c = t % C;
    int g = k >> 3, j = k & 7;
    Wt[c * 128 + ((g ^ (c & 7)) << 3) + j] = bf16_rne(W[t]);
}

// ---- MFMA GEMM: Y[nrows x OUTF](bf16) = X[nrows x 128] @ W[128 x OUTF] ----

template <int OUTF, bool INBF>
__global__ __launch_bounds__(256) void gemm_mfma_k(const void* __restrict__ Xv,
                                                   const unsigned short* __restrict__ Wt,
                                                   unsigned short* __restrict__ Y, int nrows) {
    constexpr int CT = OUTF / 16;
    __shared__ short lds_w[OUTF * 128];
    int tid = threadIdx.x;
    {
        const uint4* srcp = (const uint4*)Wt;
        uint4* dstp = (uint4*)lds_w;
        for (int i = tid; i < OUTF * 16; i += 256) dstp[i] = srcp[i];
    }
    __syncthreads();
    int lane = tid & 63;
    int r16 = lane & 15, kq = lane >> 4;
    int rbase = blockIdx.x * 128 + (tid >> 6) * 32;
    f32x4 acc[2][CT] = {};
#pragma unroll
    for (int kk = 0; kk < 4; ++kk) {
        int k0 = kk * 32 + kq * 8;
        bf16x8 a[2];
#pragma unroll
        for (int rt = 0; rt < 2; ++rt) {
            int row = rbase + rt * 16 + r16;
            if (row < nrows) {
                if constexpr (INBF) {
                    a[rt] = *(const bf16x8*)((const unsigned short*)Xv + (size_t)row * 128 + k0);
                } else {
                    const float* xp = (const float*)Xv + (size_t)row * 128 + k0;
                    float4 f0 = *(const float4*)xp;
                    float4 f1 = *(const float4*)(xp + 4);
                    uint4 uu = make_uint4(pack_bf16x2(f0.x, f0.y), pack_bf16x2(f0.z, f0.w),
                                          pack_bf16x2(f1.x, f1.y), pack_bf16x2(f1.z, f1.w));
                    a[rt] = *(bf16x8*)&uu;
                }
            } else {
                bf16x8 z = {0, 0, 0, 0, 0, 0, 0, 0};
                a[rt] = z;
            }
        }
#pragma unroll
        for (int c = 0; c < CT; ++c) {
            int col = c * 16 + r16;
            int gp = (kk * 4 + kq) ^ (col & 7);
            bf16x8 b = *(const bf16x8*)&lds_w[col * 128 + gp * 8];
            acc[0][c] = __builtin_amdgcn_mfma_f32_16x16x32_bf16(a[0], b, acc[0][c], 0, 0, 0);
            acc[1][c] = __builtin_amdgcn_mfma_f32_16x16x32_bf16(a[1], b, acc[1][c], 0, 0, 0);
        }
    }
#pragma unroll
    for (int rt = 0; rt < 2; ++rt) {
#pragma unroll
        for (int c = 0; c < CT; ++c) {
#pragma unroll
            for (int r = 0; r < 4; ++r) {
                int row = rbase + rt * 16 + kq * 4 + r;
                if (row < nrows)
                    Y[(size_t)row * OUTF + c * 16 + r16] = bf16_rne(acc[rt][c][r]);
            }
        }
    }
}

// ---------------- Aggregation (fused bias + PReLU), 16-lane edge groups ----------------
// 32-bit saddr+voffset addressing; packed f32 accumulate (v_pk_fma_f32).

// Layer 1: row = 128 bf16 = 256 B. 4 edges/wave concurrently (16 lanes x uint4 each).
__global__ void agg1_k(const unsigned* __restrict__ hw, const int* __restrict__ row_start,
                       const uint2* __restrict__ edge, const float* __restrict__ dis,
                       const float* __restrict__ bias, const float* __restrict__ aslope,
                       unsigned* __restrict__ out, int n) {
    int wid = (blockIdx.x * 256 + threadIdx.x) >> 6;
    int lane = threadIdx.x & 63;
    if (wid >= n) return;
    int g = lane >> 4;                       // edge slot 0..3
    unsigned li = lane & 15;                 // 16B granule
    unsigned rowoff = li << 4;               // byte offset within 256B row
    const char* hwb = (const char*)hw;
    const char* edb = (const char*)edge;
    f32x2 acc[4] = {};
    int e0 = row_start[wid], e1 = row_start[wid + 1];
    for (int e = e0; e < e1; e += 16) {
        uint2 ed[4];
        uint4 v[4];
#pragma unroll
        for (int u = 0; u < 4; ++u) {
            int ee = e + u * 4 + g;
            unsigned ec = (unsigned)((ee < e1) ? ee : (e1 - 1));
            ed[u] = *(const uint2*)(edb + (ec << 3));
        }
#pragma unroll
        for (int u = 0; u < 4; ++u)
            v[u] = *(const uint4*)(hwb + ((ed[u].x << 8) | rowoff));
#pragma unroll
        for (int u = 0; u < 4; ++u) {
            float nr = (e + u * 4 + g < e1) ? __uint_as_float(ed[u].y) : 0.f;
            f32x2 nr2 = {nr, nr};
            acc[0] += unpk(v[u].x) * nr2;
            acc[1] += unpk(v[u].y) * nr2;
            acc[2] += unpk(v[u].z) * nr2;
            acc[3] += unpk(v[u].w) * nr2;
        }
    }
#pragma unroll
    for (int j = 0; j < 4; ++j) {
        acc[j].x += __shfl_xor(acc[j].x, 16, 64);
        acc[j].y += __shfl_xor(acc[j].y, 16, 64);
        acc[j].x += __shfl_xor(acc[j].x, 32, 64);
        acc[j].y += __shfl_xor(acc[j].y, 32, 64);
    }
    if (g == 0) {
        float dn = dis[wid];
        f32x2 sw2 = {dn * dn, dn * dn};
        uint4 v = *(const uint4*)(hwb + (((unsigned)wid << 8) | rowoff));
        acc[0] += unpk(v.x) * sw2;
        acc[1] += unpk(v.y) * sw2;
        acc[2] += unpk(v.z) * sw2;
        acc[3] += unpk(v.w) * sw2;
        float4 b0 = ((const float4*)bias)[li * 2];
        float4 b1 = ((const float4*)bias)[li * 2 + 1];
        float al = aslope[0];
        float r[8] = {acc[0].x + b0.x, acc[0].y + b0.y, acc[1].x + b0.z, acc[1].y + b0.w,
                      acc[2].x + b1.x, acc[2].y + b1.y, acc[3].x + b1.z, acc[3].y + b1.w};
#pragma unroll
        for (int j = 0; j < 8; ++j) r[j] = (r[j] >= 0.f) ? r[j] : al * r[j];
        uint4 o = make_uint4(pack_bf16x2(r[0], r[1]), pack_bf16x2(r[2], r[3]),
                             pack_bf16x2(r[4], r[5]), pack_bf16x2(r[6], r[7]));
        *(uint4*)(out + (size_t)wid * 64 + li * 4) = o;
    }
}

// Layer 2: row = 64 bf16 = 128 B. 4 edges/wave (16 lanes x uint2); f32 output.
__global__ void agg2_k(const unsigned* __restrict__ hw, const int* __restrict__ row_start,
                       const uint2* __restrict__ edge, const float* __restrict__ dis,
                       const float* __restrict__ bias, const float* __restrict__ aslope,
                       float* __restrict__ out, int n) {
    int wid = (blockIdx.x * 256 + threadIdx.x) >> 6;
    int lane = threadIdx.x & 63;
    if (wid >= n) return;
    int g = lane >> 4;                       // edge slot 0..3
    unsigned li = lane & 15;                 // 8B granule
    unsigned rowoff = li << 3;               // byte offset within 128B row
    const char* hwb = (const char*)hw;
    const char* edb = (const char*)edge;
    f32x2 acc[2] = {};
    int e0 = row_start[wid], e1 = row_start[wid + 1];
    for (int e = e0; e < e1; e += 16) {
        uint2 ed[4];
        uint2 v[4];
#pragma unroll
        for (int u = 0; u < 4; ++u) {
            int ee = e + u * 4 + g;
            unsigned ec = (unsigned)((ee < e1) ? ee : (e1 - 1));
            ed[u] = *(const uint2*)(edb + (ec << 3));
        }
#pragma unroll
        for (int u = 0; u < 4; ++u)
            v[u] = *(const uint2*)(hwb + ((ed[u].x << 7) | rowoff));
#pragma unroll
        for (int u = 0; u < 4; ++u) {
            float nr = (e + u * 4 + g < e1) ? __uint_as_float(ed[u].y) : 0.f;
            f32x2 nr2 = {nr, nr};
            acc[0] += unpk(v[u].x) * nr2;
            acc[1] += unpk(v[u].y) * nr2;
        }
    }
#pragma unroll
    for (int j = 0; j < 2; ++j) {
        acc[j].x += __shfl_xor(acc[j].x, 16, 64);
        acc[j].y += __shfl_xor(acc[j].y, 16, 64);
        acc[j].x += __shfl_xor(acc[j].x, 32, 64);
        acc[j].y += __shfl_xor(acc[j].y, 32, 64);
    }
    if (g == 0) {
        float dn = dis[wid];
        f32x2 sw2 = {dn * dn, dn * dn};
        uint2 v = *(const uint2*)(hwb + (((unsigned)wid << 7) | rowoff));
        acc[0] += unpk(v.x) * sw2;
        acc[1] += unpk(v.y) * sw2;
        float4 b = ((const float4*)bias)[li];
        float al = aslope[0];
        float r[4] = {acc[0].x + b.x, acc[0].y + b.y, acc[1].x + b.z, acc[1].y + b.w};
#pragma unroll
        for (int j = 0; j < 4; ++j) r[j] = (r[j] >= 0.f) ? r[j] : al * r[j];
        *(float4*)(out + (size_t)wid * 64 + li * 4) = make_float4(r[0], r[1], r[2], r[3]);
    }
}

// ---------------- launch ----------------

extern "C" void kernel_launch(void* const* d_in, const int* in_sizes, int n_in,
                              void* d_out, int out_size, void* d_ws, size_t ws_size,
                              hipStream_t stream) {
    const float* x  = (const float*)d_in[0];
    const int*   ei = (const int*)d_in[1];
    const int*   src = ei;
    const int*   dst = ei + N_EDGES;
    const float* W1 = (const float*)d_in[2];
    const float* b1 = (const float*)d_in[3];
    const float* W2 = (const float*)d_in[4];
    const float* b2 = (const float*)d_in[5];
    const float* a  = (const float*)d_in[6];
    float* out = (float*)d_out;

    char* ws = (char*)d_ws;
    size_t off = 0;
    auto alloc = [&](size_t bytes) -> void* {
        void* p = ws + off;
        off += (bytes + 255) & ~(size_t)255;
        return p;
    };
    int*            row_start = (int*)alloc((size_t)(N_NODES + 1) * 4);
    float*          dis       = (float*)alloc((size_t)N_NODES * 4);
    int*            cursor    = (int*)alloc(NB * 4);
    int*            bbase     = (int*)alloc(NB * 4);
    unsigned*       binned    = (unsigned*)alloc((size_t)NB * (1 << CAPSH) * 4);  // 12.8 MB
    uint2*          edge      = (uint2*)alloc((size_t)N_EDGES * 8);
    unsigned*       hw1       = (unsigned*)alloc((size_t)N_NODES * 64 * 4);  // bf16 [N,128]
    unsigned*       hbuf      = (unsigned*)alloc((size_t)N_NODES * 64 * 4);  // bf16 [N,128]
    unsigned*       hw2       = (unsigned*)alloc((size_t)N_NODES * 32 * 4);  // bf16 [N,64]
    unsigned short* Wt1       = (unsigned short*)alloc(128 * 128 * 2);
    unsigned short* Wt2       = (unsigned short*)alloc(64 * 128 * 2);

    int gB = (N_EDGES + EPB - 1) / EPB;      // 391

    wt_k<<<64, 256, 0, stream>>>(W1, Wt1, 128);
    wt_k<<<32, 256, 0, stream>>>(W2, Wt2, 64);

    cursor_init_k<<<1, 256, 0, stream>>>(cursor);
    bin_k<<<gB, 256, 0, stream>>>(src, dst, cursor, binned, N_EDGES);
    bucket_scan_k<<<1, 256, 0, stream>>>(cursor, bbase);
    deg_dis_k<<<NB, 256, 0, stream>>>(binned, cursor, bbase, row_start, dis, N_NODES, N_EDGES);
    csr_k<<<NB, 256, 0, stream>>>(binned, cursor, row_start, dis, edge, N_NODES);

    int gG = (N_NODES + 127) / 128;   // 782
    int gA = (N_NODES + 3) / 4;       // 25000 (4 waves/block, 1 wave/node)

    gemm_mfma_k<128, false><<<gG, 256, 0, stream>>>(x, Wt1, (unsigned short*)hw1, N_NODES);
    agg1_k<<<gA, 256, 0, stream>>>(hw1, row_start, edge, dis, b1, a, hbuf, N_NODES);
    gemm_mfma_k<64, true><<<gG, 256, 0, stream>>>(hbuf, Wt2, (unsigned short*)hw2, N_NODES);
    agg2_k<<<gA, 256, 0, stream>>>(hw2, row_start, edge, dis, b2, a, out, N_NODES);
}

// Round 9
// 186.406 us; speedup vs baseline: 3.6651x; 1.1138x over previous
//
#include <hip/hip_runtime.h>

#define N_NODES 100000
#define N_EDGES 1600000
#define BSH 9                      // 512 nodes per bucket
#define NB  196                    // ceil(N_NODES / 512)
#define EPB 4096                   // edges per bin block
#define CAPSH 14                   // 16384 binned slots per bucket (avg fill ~8163)
#define GB  ((N_EDGES + EPB - 1) / EPB)     // 391 bin blocks
#define GG  ((N_NODES + 127) / 128)         // 782 gemm blocks

typedef short bf16x8 __attribute__((ext_vector_type(8)));
typedef float f32x4 __attribute__((ext_vector_type(4)));
typedef float f32x2 __attribute__((ext_vector_type(2)));

// ---------------- bf16 helpers (storage only; math in f32) ----------------

__device__ __forceinline__ unsigned pack_bf16x2(float a, float b) {
    unsigned ua = __float_as_uint(a), ub = __float_as_uint(b);
    unsigned ra = (ua + 0x7fffu + ((ua >> 16) & 1u)) >> 16;   // RNE
    unsigned rb = (ub + 0x7fffu + ((ub >> 16) & 1u)) >> 16;
    return ra | (rb << 16);
}
__device__ __forceinline__ unsigned short bf16_rne(float f) {
    unsigned u = __float_as_uint(f);
    return (unsigned short)((u + 0x7fffu + ((u >> 16) & 1u)) >> 16);
}
__device__ __forceinline__ f32x2 unpk(unsigned u) {
    f32x2 r;
    r.x = __uint_as_float(u << 16);
    r.y = __uint_as_float(u & 0xffff0000u);
    return r;
}

// ---- setup: W transforms + cursor init in one launch ----
// W[128][C] f32 -> Wt[C][128] bf16 with 16B-granule XOR swizzle:
// element (k,c) at Wt[c*128 + ((k>>3) ^ (c&7))*8 + (k&7)]

__device__ __forceinline__ void wt_body(const float* W, unsigned short* Wt, int C, int bid) {
    int t = bid * 256 + threadIdx.x;
    if (t >= 128 * C) return;
    int k = t / C, c = t % C;
    int g = k >> 3, j = k & 7;
    Wt[c * 128 + ((g ^ (c & 7)) << 3) + j] = bf16_rne(W[t]);
}

__global__ void setup_k(const float* __restrict__ W1, unsigned short* __restrict__ Wt1,
                        const float* __restrict__ W2, unsigned short* __restrict__ Wt2,
                        int* __restrict__ cursor) {
    int b = blockIdx.x;
    if (b < 64) { wt_body(W1, Wt1, 128, b); }
    else if (b < 96) { wt_body(W2, Wt2, 64, b - 64); }
    else {
        int t = threadIdx.x;
        if (t < NB) cursor[t] = t << CAPSH;
    }
}

// ---- fused: bin (blocks 0..GB-1)  ||  gemm1 (blocks GB..GB+GG-1) ----

__global__ __launch_bounds__(256) void bin_gemm1_k(
        const int* __restrict__ src, const int* __restrict__ dst,
        int* __restrict__ cursor, unsigned* __restrict__ binned,
        const float* __restrict__ X, const unsigned short* __restrict__ Wt,
        unsigned short* __restrict__ Y) {
    __shared__ int lhist[256];
    __shared__ int lcur[256];
    __shared__ short lds_w[128 * 128];   // 32 KB (gemm branch)
    int tid = threadIdx.x;

    if (blockIdx.x < GB) {
        // ---------- bin: two-pass per block (hist -> alloc -> place) ----------
        lhist[tid] = 0;
        __syncthreads();
        int e0 = blockIdx.x * EPB;
#pragma unroll
        for (int i = 0; i < EPB / 256; ++i) {
            int e = e0 + i * 256 + tid;
            if (e < N_EDGES) atomicAdd(&lhist[dst[e] >> BSH], 1);
        }
        __syncthreads();
        {
            int c = lhist[tid];
            lcur[tid] = (tid < NB && c > 0) ? atomicAdd(&cursor[tid], c) : 0;
        }
        __syncthreads();
#pragma unroll
        for (int i = 0; i < EPB / 256; ++i) {
            int e = e0 + i * 256 + tid;
            if (e < N_EDGES) {
                int d = dst[e];
                int b = d >> BSH;
                int pos = atomicAdd(&lcur[b], 1);
                if (pos < ((b + 1) << CAPSH))   // capacity guard (never hits here)
                    binned[pos] = ((unsigned)(d & ((1 << BSH) - 1)) << 17) | (unsigned)src[e];
            }
        }
        return;
    }

    // ---------- gemm1: hw1[N,128](bf16) = X[N,128](f32) @ W1 ----------
    {
        const uint4* srcp = (const uint4*)Wt;
        uint4* dstp = (uint4*)lds_w;
        for (int i = tid; i < 128 * 16; i += 256) dstp[i] = srcp[i];
    }
    __syncthreads();
    int lane = tid & 63;
    int r16 = lane & 15, kq = lane >> 4;
    int rbase = (blockIdx.x - GB) * 128 + (tid >> 6) * 32;
    f32x4 acc[2][8] = {};
#pragma unroll
    for (int kk = 0; kk < 4; ++kk) {
        int k0 = kk * 32 + kq * 8;
        bf16x8 a[2];
#pragma unroll
        for (int rt = 0; rt < 2; ++rt) {
            int row = rbase + rt * 16 + r16;
            if (row < N_NODES) {
                const float* xp = X + (size_t)row * 128 + k0;
                float4 f0 = *(const float4*)xp;
                float4 f1 = *(const float4*)(xp + 4);
                uint4 uu = make_uint4(pack_bf16x2(f0.x, f0.y), pack_bf16x2(f0.z, f0.w),
                                      pack_bf16x2(f1.x, f1.y), pack_bf16x2(f1.z, f1.w));
                a[rt] = *(bf16x8*)&uu;
            } else {
                bf16x8 z = {0, 0, 0, 0, 0, 0, 0, 0};
                a[rt] = z;
            }
        }
#pragma unroll
        for (int c = 0; c < 8; ++c) {
            int col = c * 16 + r16;
            int gp = (kk * 4 + kq) ^ (col & 7);
            bf16x8 b = *(const bf16x8*)&lds_w[col * 128 + gp * 8];
            acc[0][c] = __builtin_amdgcn_mfma_f32_16x16x32_bf16(a[0], b, acc[0][c], 0, 0, 0);
            acc[1][c] = __builtin_amdgcn_mfma_f32_16x16x32_bf16(a[1], b, acc[1][c], 0, 0, 0);
        }
    }
#pragma unroll
    for (int rt = 0; rt < 2; ++rt) {
#pragma unroll
        for (int c = 0; c < 8; ++c) {
#pragma unroll
            for (int r = 0; r < 4; ++r) {
                int row = rbase + rt * 16 + kq * 4 + r;
                if (row < N_NODES)
                    Y[(size_t)row * 128 + c * 16 + r16] = bf16_rne(acc[rt][c][r]);
            }
        }
    }
}

// Bucket totals -> exclusive scan -> global bucket base offsets.
__global__ void bucket_scan_k(const int* __restrict__ cursor, int* __restrict__ bucket_base) {
    __shared__ int s[256];
    int tid = threadIdx.x;
    int v = (tid < NB) ? (cursor[tid] - (tid << CAPSH)) : 0;
    s[tid] = v; __syncthreads();
    for (int off = 1; off < 256; off <<= 1) {
        int t = 0;
        if (tid >= off) t = s[tid - off];
        __syncthreads();
        s[tid] += t;
        __syncthreads();
    }
    if (tid < NB) bucket_base[tid] = s[tid] - v;
}

// Per-bucket: count degrees in LDS, local scan -> row_start, dis = rsqrt(deg+1).
__global__ __launch_bounds__(256) void deg_dis_k(const unsigned* __restrict__ binned,
                                                 const int* __restrict__ cursor,
                                                 const int* __restrict__ bucket_base,
                                                 int* __restrict__ row_start,
                                                 float* __restrict__ dis, int n, int E) {
    __shared__ int lcnt[1 << BSH];
    __shared__ int ls[256];
    int b = blockIdx.x, tid = threadIdx.x;
    for (int j = tid; j < (1 << BSH); j += 256) lcnt[j] = 0;
    __syncthreads();
    int base = b << CAPSH;
    int total = cursor[b] - base;
    for (int i = tid; i < total; i += 256)
        atomicAdd(&lcnt[binned[base + i] >> 17], 1);
    __syncthreads();
    int v0 = lcnt[2 * tid], v1 = lcnt[2 * tid + 1];
    int sv = v0 + v1;
    ls[tid] = sv;
    __syncthreads();
    for (int off = 1; off < 256; off <<= 1) {
        int t = 0;
        if (tid >= off) t = ls[tid - off];
        __syncthreads();
        ls[tid] += t;
        __syncthreads();
    }
    int pre = ls[tid] - sv;   // exclusive prefix over node pairs
    int nbase = b << BSH;
    int bb = bucket_base[b];
    int node0 = nbase + 2 * tid, node1 = node0 + 1;
    if (node0 < n) {
        row_start[node0] = bb + pre;
        dis[node0] = rsqrtf((float)(v0 + 1));
    }
    if (node1 < n) {
        row_start[node1] = bb + pre + v0;
        dis[node1] = rsqrtf((float)(v1 + 1));
    }
    if (b == NB - 1 && tid == 255) row_start[n] = E;
}

// Place binned edges at exact CSR slots (bucket-local writes).
__global__ __launch_bounds__(256) void csr_k(const unsigned* __restrict__ binned,
                                             const int* __restrict__ cursor,
                                             const int* __restrict__ row_start,
                                             const float* __restrict__ dis,
                                             uint2* __restrict__ edge, int n) {
    __shared__ int lfill[1 << BSH];
    int b = blockIdx.x, tid = threadIdx.x;
    int nbase = b << BSH;
    for (int j = tid; j < (1 << BSH); j += 256) {
        int node = nbase + j;
        lfill[j] = (node < n) ? row_start[node] : 0;
    }
    __syncthreads();
    int base = b << CAPSH;
    int total = cursor[b] - base;
    for (int i = base + tid; i < base + total; i += 256) {
        unsigned u = binned[i];
        int s = u & 0x1FFFFu;
        int dl = u >> 17;
        int pos = atomicAdd(&lfill[dl], 1);
        edge[pos] = make_uint2((unsigned)s, __float_as_uint(dis[s] * dis[nbase + dl]));
    }
}

// ---- MFMA GEMM (layer 2): hw2[N,64](bf16) = h[N,128](bf16) @ W2 ----

__global__ __launch_bounds__(256) void gemm2_k(const unsigned short* __restrict__ Xv,
                                               const unsigned short* __restrict__ Wt,
                                               unsigned short* __restrict__ Y, int nrows) {
    __shared__ short lds_w[64 * 128];
    int tid = threadIdx.x;
    {
        const uint4* srcp = (const uint4*)Wt;
        uint4* dstp = (uint4*)lds_w;
        for (int i = tid; i < 64 * 16; i += 256) dstp[i] = srcp[i];
    }
    __syncthreads();
    int lane = tid & 63;
    int r16 = lane & 15, kq = lane >> 4;
    int rbase = blockIdx.x * 128 + (tid >> 6) * 32;
    f32x4 acc[2][4] = {};
#pragma unroll
    for (int kk = 0; kk < 4; ++kk) {
        int k0 = kk * 32 + kq * 8;
        bf16x8 a[2];
#pragma unroll
        for (int rt = 0; rt < 2; ++rt) {
            int row = rbase + rt * 16 + r16;
            if (row < nrows) {
                a[rt] = *(const bf16x8*)(Xv + (size_t)row * 128 + k0);
            } else {
                bf16x8 z = {0, 0, 0, 0, 0, 0, 0, 0};
                a[rt] = z;
            }
        }
#pragma unroll
        for (int c = 0; c < 4; ++c) {
            int col = c * 16 + r16;
            int gp = (kk * 4 + kq) ^ (col & 7);
            bf16x8 b = *(const bf16x8*)&lds_w[col * 128 + gp * 8];
            acc[0][c] = __builtin_amdgcn_mfma_f32_16x16x32_bf16(a[0], b, acc[0][c], 0, 0, 0);
            acc[1][c] = __builtin_amdgcn_mfma_f32_16x16x32_bf16(a[1], b, acc[1][c], 0, 0, 0);
        }
    }
#pragma unroll
    for (int rt = 0; rt < 2; ++rt) {
#pragma unroll
        for (int c = 0; c < 4; ++c) {
#pragma unroll
            for (int r = 0; r < 4; ++r) {
                int row = rbase + rt * 16 + kq * 4 + r;
                if (row < nrows)
                    Y[(size_t)row * 64 + c * 16 + r16] = bf16_rne(acc[rt][c][r]);
            }
        }
    }
}

// ---------------- Aggregation: one node per 16-lane group, no shuffles ----------------
// 4 nodes/wave; each group covers the full row (16 lanes), 4 edges in flight.

// Layer 1: row = 128 bf16 = 256 B = 16 lanes x uint4. Output h in bf16.
__global__ void agg1_k(const unsigned* __restrict__ hw, const int* __restrict__ row_start,
                       const uint2* __restrict__ edge, const float* __restrict__ dis,
                       const float* __restrict__ bias, const float* __restrict__ aslope,
                       unsigned* __restrict__ out, int n) {
    int w = (blockIdx.x * 256 + threadIdx.x) >> 6;
    int lane = threadIdx.x & 63;
    int g = lane >> 4;
    unsigned li = lane & 15;
    int node = w * 4 + g;
    bool valid = node < n;
    int e0 = valid ? row_start[node] : 0;
    int e1 = valid ? row_start[node + 1] : 0;
    unsigned rowoff = li << 4;
    const char* hwb = (const char*)hw;
    const char* edb = (const char*)edge;
    f32x2 acc[4] = {};
    int e = e0;
    while (__any(e < e1)) {
        if (e < e1) {
            uint2 ed[4];
            uint4 v[4];
#pragma unroll
            for (int u = 0; u < 4; ++u) {
                int ee = e + u;
                unsigned ec = (unsigned)((ee < e1) ? ee : (e1 - 1));
                ed[u] = *(const uint2*)(edb + (ec << 3));
            }
#pragma unroll
            for (int u = 0; u < 4; ++u)
                v[u] = *(const uint4*)(hwb + ((ed[u].x << 8) | rowoff));
#pragma unroll
            for (int u = 0; u < 4; ++u) {
                float nr = (e + u < e1) ? __uint_as_float(ed[u].y) : 0.f;
                f32x2 nr2 = {nr, nr};
                acc[0] += unpk(v[u].x) * nr2;
                acc[1] += unpk(v[u].y) * nr2;
                acc[2] += unpk(v[u].z) * nr2;
                acc[3] += unpk(v[u].w) * nr2;
            }
        }
        e += 4;
    }
    if (valid) {
        float dn = dis[node];
        f32x2 sw2 = {dn * dn, dn * dn};
        uint4 v = *(const uint4*)(hwb + (((unsigned)node << 8) | rowoff));
        acc[0] += unpk(v.x) * sw2;
        acc[1] += unpk(v.y) * sw2;
        acc[2] += unpk(v.z) * sw2;
        acc[3] += unpk(v.w) * sw2;
        float4 b0 = ((const float4*)bias)[li * 2];
        float4 b1 = ((const float4*)bias)[li * 2 + 1];
        float al = aslope[0];
        float r[8] = {acc[0].x + b0.x, acc[0].y + b0.y, acc[1].x + b0.z, acc[1].y + b0.w,
                      acc[2].x + b1.x, acc[2].y + b1.y, acc[3].x + b1.z, acc[3].y + b1.w};
#pragma unroll
        for (int j = 0; j < 8; ++j) r[j] = (r[j] >= 0.f) ? r[j] : al * r[j];
        uint4 o = make_uint4(pack_bf16x2(r[0], r[1]), pack_bf16x2(r[2], r[3]),
                             pack_bf16x2(r[4], r[5]), pack_bf16x2(r[6], r[7]));
        *(uint4*)(out + (size_t)node * 64 + li * 4) = o;
    }
}

// Layer 2: row = 64 bf16 = 128 B = 16 lanes x uint2. Output f32.
__global__ void agg2_k(const unsigned* __restrict__ hw, const int* __restrict__ row_start,
                       const uint2* __restrict__ edge, const float* __restrict__ dis,
                       const float* __restrict__ bias, const float* __restrict__ aslope,
                       float* __restrict__ out, int n) {
    int w = (blockIdx.x * 256 + threadIdx.x) >> 6;
    int lane = threadIdx.x & 63;
    int g = lane >> 4;
    unsigned li = lane & 15;
    int node = w * 4 + g;
    bool valid = node < n;
    int e0 = valid ? row_start[node] : 0;
    int e1 = valid ? row_start[node + 1] : 0;
    unsigned rowoff = li << 3;
    const char* hwb = (const char*)hw;
    const char* edb = (const char*)edge;
    f32x2 acc[2] = {};
    int e = e0;
    while (__any(e < e1)) {
        if (e < e1) {
            uint2 ed[4];
            uint2 v[4];
#pragma unroll
            for (int u = 0; u < 4; ++u) {
                int ee = e + u;
                unsigned ec = (unsigned)((ee < e1) ? ee : (e1 - 1));
                ed[u] = *(const uint2*)(edb + (ec << 3));
            }
#pragma unroll
            for (int u = 0; u < 4; ++u)
                v[u] = *(const uint2*)(hwb + ((ed[u].x << 7) | rowoff));
#pragma unroll
            for (int u = 0; u < 4; ++u) {
                float nr = (e + u < e1) ? __uint_as_float(ed[u].y) : 0.f;
                f32x2 nr2 = {nr, nr};
                acc[0] += unpk(v[u].x) * nr2;
                acc[1] += unpk(v[u].y) * nr2;
            }
        }
        e += 4;
    }
    if (valid) {
        float dn = dis[node];
        f32x2 sw2 = {dn * dn, dn * dn};
        uint2 v = *(const uint2*)(hwb + (((unsigned)node << 7) | rowoff));
        acc[0] += unpk(v.x) * sw2;
        acc[1] += unpk(v.y) * sw2;
        float4 b = ((const float4*)bias)[li];
        float al = aslope[0];
        float r[4] = {acc[0].x + b.x, acc[0].y + b.y, acc[1].x + b.z, acc[1].y + b.w};
#pragma unroll
        for (int j = 0; j < 4; ++j) r[j] = (r[j] >= 0.f) ? r[j] : al * r[j];
        *(float4*)(out + (size_t)node * 64 + li * 4) = make_float4(r[0], r[1], r[2], r[3]);
    }
}

// ---------------- launch ----------------

extern "C" void kernel_launch(void* const* d_in, const int* in_sizes, int n_in,
                              void* d_out, int out_size, void* d_ws, size_t ws_size,
                              hipStream_t stream) {
    const float* x  = (const float*)d_in[0];
    const int*   ei = (const int*)d_in[1];
    const int*   src = ei;
    const int*   dst = ei + N_EDGES;
    const float* W1 = (const float*)d_in[2];
    const float* b1 = (const float*)d_in[3];
    const float* W2 = (const float*)d_in[4];
    const float* b2 = (const float*)d_in[5];
    const float* a  = (const float*)d_in[6];
    float* out = (float*)d_out;

    char* ws = (char*)d_ws;
    size_t off = 0;
    auto alloc = [&](size_t bytes) -> void* {
        void* p = ws + off;
        off += (bytes + 255) & ~(size_t)255;
        return p;
    };
    int*            row_start = (int*)alloc((size_t)(N_NODES + 1) * 4);
    float*          dis       = (float*)alloc((size_t)N_NODES * 4);
    int*            cursor    = (int*)alloc(NB * 4);
    int*            bbase     = (int*)alloc(NB * 4);
    unsigned*       binned    = (unsigned*)alloc((size_t)NB * (1 << CAPSH) * 4);  // 12.8 MB
    uint2*          edge      = (uint2*)alloc((size_t)N_EDGES * 8);
    unsigned*       hw1       = (unsigned*)alloc((size_t)N_NODES * 64 * 4);  // bf16 [N,128]
    unsigned*       hbuf      = (unsigned*)alloc((size_t)N_NODES * 64 * 4);  // bf16 [N,128]
    unsigned*       hw2       = (unsigned*)alloc((size_t)N_NODES * 32 * 4);  // bf16 [N,64]
    unsigned short* Wt1       = (unsigned short*)alloc(128 * 128 * 2);
    unsigned short* Wt2       = (unsigned short*)alloc(64 * 128 * 2);

    setup_k<<<97, 256, 0, stream>>>(W1, Wt1, W2, Wt2, cursor);
    bin_gemm1_k<<<GB + GG, 256, 0, stream>>>(src, dst, cursor, binned,
                                             x, Wt1, (unsigned short*)hw1);
    bucket_scan_k<<<1, 256, 0, stream>>>(cursor, bbase);
    deg_dis_k<<<NB, 256, 0, stream>>>(binned, cursor, bbase, row_start, dis, N_NODES, N_EDGES);
    csr_k<<<NB, 256, 0, stream>>>(binned, cursor, row_start, dis, edge, N_NODES);

    int gA = (N_NODES + 1023) / 1024;   // 98 -> 6250 blocks? no: waves=25000 -> blocks 6250
    gA = (N_NODES / 4 + 3) / 4;         // 6250 blocks (4 waves/block, 4 nodes/wave)

    agg1_k<<<6250, 256, 0, stream>>>(hw1, row_start, edge, dis, b1, a, hbuf, N_NODES);
    gemm2_k<<<GG, 256, 0, stream>>>((unsigned short*)hbuf, Wt2, (unsigned short*)hw2, N_NODES);
    agg2_k<<<6250, 256, 0, stream>>>(hw2, row_start, edge, dis, b2, a, out, N_NODES);
    (void)gA;
}